// Round 1
// baseline (5501.138 us; speedup 1.0000x reference)
//
#include <hip/hip_runtime.h>
#include <math.h>

// Problem constants (fixed by the reference; scalar inputs batch_size/num_obj ignored)
constexpr int kB    = 64;
constexpr int kN    = 36;
constexpr int kBN   = kB * kN;   // 2304
constexpr int kD    = 2048;
constexpr int kDatt = 512;

constexpr int TBM = 64, TBN = 64, TBK = 16;

// ---------------------------------------------------------------------------
// K1: fused = (A1@B1) .* (A2@B2), M=2304 N=2048 K=2048, all row-major fp32
// ---------------------------------------------------------------------------
__global__ __launch_bounds__(256)
void k1_fused_gemm(const float* __restrict__ A1, const float* __restrict__ B1,
                   const float* __restrict__ A2, const float* __restrict__ B2,
                   float* __restrict__ C)
{
    __shared__ float As1[TBK][TBM + 4];
    __shared__ float As2[TBK][TBM + 4];
    __shared__ float Bs1[TBK][TBN + 4];
    __shared__ float Bs2[TBK][TBN + 4];

    const int tid = threadIdx.x;
    const int tx = tid & 15, ty = tid >> 4;
    const int row0 = blockIdx.y * TBM;
    const int col0 = blockIdx.x * TBN;

    const int la_k = tid & 15, la_m = tid >> 4;   // A-tile loader coords
    const int lb_n = tid & 63, lb_k = tid >> 6;   // B-tile loader coords

    float acc1[4][4] = {{0.f}}, acc2[4][4] = {{0.f}};

    for (int k0 = 0; k0 < kD; k0 += TBK) {
        #pragma unroll
        for (int mm = 0; mm < TBM; mm += 16) {
            As1[la_k][la_m + mm] = A1[(size_t)(row0 + la_m + mm) * kD + k0 + la_k];
            As2[la_k][la_m + mm] = A2[(size_t)(row0 + la_m + mm) * kD + k0 + la_k];
        }
        #pragma unroll
        for (int kk = 0; kk < TBK; kk += 4) {
            Bs1[lb_k + kk][lb_n] = B1[(size_t)(k0 + lb_k + kk) * kD + col0 + lb_n];
            Bs2[lb_k + kk][lb_n] = B2[(size_t)(k0 + lb_k + kk) * kD + col0 + lb_n];
        }
        __syncthreads();
        #pragma unroll
        for (int kk = 0; kk < TBK; ++kk) {
            float4 a1 = *(const float4*)&As1[kk][ty * 4];
            float4 a2 = *(const float4*)&As2[kk][ty * 4];
            float4 b1 = *(const float4*)&Bs1[kk][tx * 4];
            float4 b2 = *(const float4*)&Bs2[kk][tx * 4];
            float a1r[4] = {a1.x, a1.y, a1.z, a1.w};
            float a2r[4] = {a2.x, a2.y, a2.z, a2.w};
            float b1r[4] = {b1.x, b1.y, b1.z, b1.w};
            float b2r[4] = {b2.x, b2.y, b2.z, b2.w};
            #pragma unroll
            for (int r = 0; r < 4; ++r)
                #pragma unroll
                for (int c = 0; c < 4; ++c) {
                    acc1[r][c] = fmaf(a1r[r], b1r[c], acc1[r][c]);
                    acc2[r][c] = fmaf(a2r[r], b2r[c], acc2[r][c]);
                }
        }
        __syncthreads();
    }
    #pragma unroll
    for (int r = 0; r < 4; ++r) {
        float4 o;
        o.x = acc1[r][0] * acc2[r][0];
        o.y = acc1[r][1] * acc2[r][1];
        o.z = acc1[r][2] * acc2[r][2];
        o.w = acc1[r][3] * acc2[r][3];
        *(float4*)&C[(size_t)(row0 + ty * 4 + r) * kD + col0 + tx * 4] = o;
    }
}

// ---------------------------------------------------------------------------
// K2: C1 = A@B1, C2 = A@B2 (shared A-operand: ra/rb projections of fused)
// ---------------------------------------------------------------------------
__global__ __launch_bounds__(256)
void k2_dual_proj(const float* __restrict__ A, const float* __restrict__ B1,
                  const float* __restrict__ B2,
                  float* __restrict__ C1, float* __restrict__ C2)
{
    __shared__ float As[TBK][TBM + 4];
    __shared__ float Bs1[TBK][TBN + 4];
    __shared__ float Bs2[TBK][TBN + 4];

    const int tid = threadIdx.x;
    const int tx = tid & 15, ty = tid >> 4;
    const int row0 = blockIdx.y * TBM;
    const int col0 = blockIdx.x * TBN;

    const int la_k = tid & 15, la_m = tid >> 4;
    const int lb_n = tid & 63, lb_k = tid >> 6;

    float acc1[4][4] = {{0.f}}, acc2[4][4] = {{0.f}};

    for (int k0 = 0; k0 < kD; k0 += TBK) {
        #pragma unroll
        for (int mm = 0; mm < TBM; mm += 16)
            As[la_k][la_m + mm] = A[(size_t)(row0 + la_m + mm) * kD + k0 + la_k];
        #pragma unroll
        for (int kk = 0; kk < TBK; kk += 4) {
            Bs1[lb_k + kk][lb_n] = B1[(size_t)(k0 + lb_k + kk) * kD + col0 + lb_n];
            Bs2[lb_k + kk][lb_n] = B2[(size_t)(k0 + lb_k + kk) * kD + col0 + lb_n];
        }
        __syncthreads();
        #pragma unroll
        for (int kk = 0; kk < TBK; ++kk) {
            float4 a = *(const float4*)&As[kk][ty * 4];
            float4 b1 = *(const float4*)&Bs1[kk][tx * 4];
            float4 b2 = *(const float4*)&Bs2[kk][tx * 4];
            float ar[4] = {a.x, a.y, a.z, a.w};
            float b1r[4] = {b1.x, b1.y, b1.z, b1.w};
            float b2r[4] = {b2.x, b2.y, b2.z, b2.w};
            #pragma unroll
            for (int r = 0; r < 4; ++r)
                #pragma unroll
                for (int c = 0; c < 4; ++c) {
                    acc1[r][c] = fmaf(ar[r], b1r[c], acc1[r][c]);
                    acc2[r][c] = fmaf(ar[r], b2r[c], acc2[r][c]);
                }
        }
        __syncthreads();
    }
    #pragma unroll
    for (int r = 0; r < 4; ++r) {
        size_t o = (size_t)(row0 + ty * 4 + r) * kD + col0 + tx * 4;
        float4 o1 = {acc1[r][0], acc1[r][1], acc1[r][2], acc1[r][3]};
        float4 o2 = {acc2[r][0], acc2[r][1], acc2[r][2], acc2[r][3]};
        *(float4*)&C1[o] = o1;
        *(float4*)&C2[o] = o2;
    }
}

// ---------------------------------------------------------------------------
// K3: ba/bb = box @ Wba/Wbb, K=4 -> elementwise
// ---------------------------------------------------------------------------
__global__ __launch_bounds__(256)
void k3_box_proj(const float* __restrict__ box, const float* __restrict__ Wba,
                 const float* __restrict__ Wbb,
                 float* __restrict__ ba, float* __restrict__ bb)
{
    const int r = blockIdx.y;
    const int c = blockIdx.x * 256 + threadIdx.x;
    const float x0 = box[r * 4 + 0], x1 = box[r * 4 + 1];
    const float x2 = box[r * 4 + 2], x3 = box[r * 4 + 3];
    float va = x0 * Wba[c] + x1 * Wba[kD + c] + x2 * Wba[2 * kD + c] + x3 * Wba[3 * kD + c];
    float vb = x0 * Wbb[c] + x1 * Wbb[kD + c] + x2 * Wbb[2 * kD + c] + x3 * Wbb[3 * kD + c];
    ba[(size_t)r * kD + c] = va;
    bb[(size_t)r * kD + c] = vb;
}

// ---------------------------------------------------------------------------
// K4: scores[b,i,j] = sum_c W1[c]*tanh(rel_{bij} . W0[:,c] + b0[c])
//     rel generated on the fly from ra_i, rb_j, ba_i, bb_j (never materialized)
//     grid: (Datt/128 chunks, 2304 (b,i) pairs); partial sums via atomicAdd.
//     b1 omitted: constant shift, softmax-invariant.
// ---------------------------------------------------------------------------
__global__ __launch_bounds__(256)
void k4_scores(const float* __restrict__ ra, const float* __restrict__ rb,
               const float* __restrict__ ba, const float* __restrict__ bb,
               const float* __restrict__ W0, const float* __restrict__ b0,
               const float* __restrict__ W1, float* __restrict__ scores)
{
    __shared__ float relS[kN][33];     // 36 x 32 (+1 pad)
    __shared__ float w0S[32][132];     // 32 x 128 (+4 pad, float4-aligned)

    const int tid = threadIdx.x;
    const int tx = tid & 31;           // column group (4 cols each)
    const int ty = tid >> 5;           // 0..7: j-row group
    const int bi = blockIdx.y;         // (b,i) pair
    const int b  = bi / kN;
    const int c0 = blockIdx.x * 128;

    float acc[5][4] = {{0.f}};

    for (int k0 = 0; k0 < kD; k0 += 32) {
        for (int idx = tid; idx < 32 * 128; idx += 256) {
            int kk = idx >> 7, cc = idx & 127;
            w0S[kk][cc] = W0[(size_t)(k0 + kk) * kDatt + c0 + cc];
        }
        {
            float rav = ra[(size_t)bi * kD + k0 + tx];
            float bav = ba[(size_t)bi * kD + k0 + tx];
            for (int j = ty; j < kN; j += 8) {
                size_t rrow = (size_t)(b * kN + j) * kD + k0 + tx;
                relS[j][tx] = rav * rb[rrow] + bav * bb[rrow];
            }
        }
        __syncthreads();
        #pragma unroll
        for (int kk = 0; kk < 32; ++kk) {
            float4 w = *(const float4*)&w0S[kk][tx * 4];
            #pragma unroll
            for (int r = 0; r < 5; ++r) {
                int j = ty + 8 * r;
                if (j < kN) {                       // wave-uniform (ty fixed per wave-half)
                    float rv = relS[j][kk];
                    acc[r][0] = fmaf(rv, w.x, acc[r][0]);
                    acc[r][1] = fmaf(rv, w.y, acc[r][1]);
                    acc[r][2] = fmaf(rv, w.z, acc[r][2]);
                    acc[r][3] = fmaf(rv, w.w, acc[r][3]);
                }
            }
        }
        __syncthreads();
    }

    const int cbase = c0 + tx * 4;
    float4 b0v = *(const float4*)&b0[cbase];
    float4 w1v = *(const float4*)&W1[cbase];
    #pragma unroll
    for (int r = 0; r < 5; ++r) {
        int j = ty + 8 * r;
        float p = 0.f;
        if (j < kN) {
            p += w1v.x * tanhf(acc[r][0] + b0v.x);
            p += w1v.y * tanhf(acc[r][1] + b0v.y);
            p += w1v.z * tanhf(acc[r][2] + b0v.z);
            p += w1v.w * tanhf(acc[r][3] + b0v.w);
        }
        #pragma unroll
        for (int off = 16; off >= 1; off >>= 1)
            p += __shfl_xor(p, off, 64);           // reduce over tx (bits 0..4 of lane)
        if (tx == 0 && j < kN)
            atomicAdd(&scores[(size_t)bi * kN + j], p);
    }
}

// ---------------------------------------------------------------------------
// K5: att[b,i,:] = softmax_j(scores[b,i,:])
// ---------------------------------------------------------------------------
__global__ __launch_bounds__(64)
void k5_softmax(const float* __restrict__ scores, float* __restrict__ att)
{
    const int bi = blockIdx.x;
    const int tid = threadIdx.x;
    float s = (tid < kN) ? scores[(size_t)bi * kN + tid] : -1e30f;
    float m = s;
    #pragma unroll
    for (int off = 32; off >= 1; off >>= 1)
        m = fmaxf(m, __shfl_xor(m, off, 64));
    float e = (tid < kN) ? expf(s - m) : 0.f;
    float sum = e;
    #pragma unroll
    for (int off = 32; off >= 1; off >>= 1)
        sum += __shfl_xor(sum, off, 64);
    if (tid < kN) att[(size_t)bi * kN + tid] = e / sum;
}

// ---------------------------------------------------------------------------
// K6: out[b,i,:] = obj + fused + ra_i.(att_i @ RB_b) + ba_i.(att_i @ BB_b)
// ---------------------------------------------------------------------------
__global__ __launch_bounds__(256)
void k6_output(const float* __restrict__ obj, const float* __restrict__ fused,
               const float* __restrict__ ra, const float* __restrict__ ba,
               const float* __restrict__ rb, const float* __restrict__ bb,
               const float* __restrict__ att, float* __restrict__ out)
{
    __shared__ float attS[kN];
    const int bi = blockIdx.x;
    const int b = bi / kN;
    const int tid = threadIdx.x;
    if (tid < kN) attS[tid] = att[(size_t)bi * kN + tid];
    __syncthreads();
    for (int d = tid; d < kD; d += 256) {
        float s1 = 0.f, s2 = 0.f;
        #pragma unroll 4
        for (int j = 0; j < kN; ++j) {
            float a = attS[j];
            size_t rrow = (size_t)(b * kN + j) * kD + d;
            s1 = fmaf(a, rb[rrow], s1);
            s2 = fmaf(a, bb[rrow], s2);
        }
        size_t o = (size_t)bi * kD + d;
        out[o] = obj[o] + fused[o] + ra[o] * s1 + ba[o] * s2;
    }
}

// ---------------------------------------------------------------------------
extern "C" void kernel_launch(void* const* d_in, const int* in_sizes, int n_in,
                              void* d_out, int out_size, void* d_ws, size_t ws_size,
                              hipStream_t stream)
{
    const float* q   = (const float*)d_in[0];   // [2304, 2048]
    const float* obj = (const float*)d_in[1];   // [64, 36, 2048]
    const float* box = (const float*)d_in[2];   // [64, 36, 4]
    const float* Wq  = (const float*)d_in[3];
    const float* Wo  = (const float*)d_in[4];
    const float* Wfa = (const float*)d_in[5];
    const float* Wfb = (const float*)d_in[6];
    const float* Wba = (const float*)d_in[7];
    const float* Wbb = (const float*)d_in[8];
    const float* W0  = (const float*)d_in[9];
    const float* b0v = (const float*)d_in[10];
    const float* W1  = (const float*)d_in[11];
    // d_in[12] = b1: softmax-invariant, unused. d_in[13..14]: scalars, unused.
    float* out = (float*)d_out;

    // Workspace layout (fp32): 5 x [2304*2048] + 2 x [2304*36]  ~= 90.6 MiB
    float* ws = (float*)d_ws;
    size_t off = 0;
    float* fused  = ws + off; off += (size_t)kBN * kD;
    float* ra     = ws + off; off += (size_t)kBN * kD;
    float* rb     = ws + off; off += (size_t)kBN * kD;
    float* ba     = ws + off; off += (size_t)kBN * kD;
    float* bb     = ws + off; off += (size_t)kBN * kD;
    float* scores = ws + off; off += (size_t)kBN * kN;
    float* att    = ws + off; off += (size_t)kBN * kN;

    hipMemsetAsync(scores, 0, (size_t)kBN * kN * sizeof(float), stream);

    dim3 gG(kD / TBN, kBN / TBM);  // (32, 36)
    k1_fused_gemm<<<gG, 256, 0, stream>>>(q, Wq, obj, Wo, fused);
    k2_dual_proj <<<gG, 256, 0, stream>>>(fused, Wfa, Wfb, ra, rb);
    k3_box_proj  <<<dim3(kD / 256, kBN), 256, 0, stream>>>(box, Wba, Wbb, ba, bb);
    k4_scores    <<<dim3(kDatt / 128, kBN), 256, 0, stream>>>(ra, rb, ba, bb, W0, b0v, W1, scores);
    k5_softmax   <<<kBN, 64, 0, stream>>>(scores, att);
    k6_output    <<<kBN, 256, 0, stream>>>(obj, fused, ra, ba, rb, bb, att, out);
}

// Round 2
// 1783.281 us; speedup vs baseline: 3.0848x; 3.0848x over previous
//
#include <hip/hip_runtime.h>
#include <hip/hip_bf16.h>
#include <math.h>

// Problem constants (fixed by the reference; scalar inputs batch_size/num_obj ignored)
constexpr int kB    = 64;
constexpr int kN    = 36;
constexpr int kBN   = kB * kN;   // 2304
constexpr int kD    = 2048;
constexpr int kDatt = 512;

constexpr int TBM = 64, TBN = 64, TBK = 16;

using bf16x8 = __attribute__((ext_vector_type(8))) short;
using f32x4  = __attribute__((ext_vector_type(4))) float;

__device__ inline unsigned short f2bf(float f) {
    union { float f; unsigned u; } v; v.f = f;
    unsigned r = v.u + 0x7FFFu + ((v.u >> 16) & 1u);   // RNE
    return (unsigned short)(r >> 16);
}

// ---------------------------------------------------------------------------
// K0: W0T[n][k] = bf16(W0[k][n])  (pre-transpose + convert, 2 MB, L2-resident)
// ---------------------------------------------------------------------------
__global__ __launch_bounds__(256)
void k0_w0t(const float* __restrict__ W0, unsigned short* __restrict__ W0T)
{
    __shared__ float T[64][65];
    const int k0 = blockIdx.x * 64;   // over kD
    const int n0 = blockIdx.y * 64;   // over kDatt
    const int c = threadIdx.x & 63, r0 = threadIdx.x >> 6;
    #pragma unroll
    for (int rr = 0; rr < 64; rr += 4)
        T[r0 + rr][c] = W0[(size_t)(k0 + r0 + rr) * kDatt + n0 + c];
    __syncthreads();
    #pragma unroll
    for (int rr = 0; rr < 64; rr += 4)
        W0T[(size_t)(n0 + r0 + rr) * kD + k0 + c] = f2bf(T[c][r0 + rr]);
}

// ---------------------------------------------------------------------------
// K1: fused = (A1@B1) .* (A2@B2), M=2304 N=2048 K=2048, all row-major fp32
// ---------------------------------------------------------------------------
__global__ __launch_bounds__(256)
void k1_fused_gemm(const float* __restrict__ A1, const float* __restrict__ B1,
                   const float* __restrict__ A2, const float* __restrict__ B2,
                   float* __restrict__ C)
{
    __shared__ float As1[TBK][TBM + 4];
    __shared__ float As2[TBK][TBM + 4];
    __shared__ float Bs1[TBK][TBN + 4];
    __shared__ float Bs2[TBK][TBN + 4];

    const int tid = threadIdx.x;
    const int tx = tid & 15, ty = tid >> 4;
    const int row0 = blockIdx.y * TBM;
    const int col0 = blockIdx.x * TBN;

    const int la_k = tid & 15, la_m = tid >> 4;
    const int lb_n = tid & 63, lb_k = tid >> 6;

    float acc1[4][4] = {{0.f}}, acc2[4][4] = {{0.f}};

    for (int k0 = 0; k0 < kD; k0 += TBK) {
        #pragma unroll
        for (int mm = 0; mm < TBM; mm += 16) {
            As1[la_k][la_m + mm] = A1[(size_t)(row0 + la_m + mm) * kD + k0 + la_k];
            As2[la_k][la_m + mm] = A2[(size_t)(row0 + la_m + mm) * kD + k0 + la_k];
        }
        #pragma unroll
        for (int kk = 0; kk < TBK; kk += 4) {
            Bs1[lb_k + kk][lb_n] = B1[(size_t)(k0 + lb_k + kk) * kD + col0 + lb_n];
            Bs2[lb_k + kk][lb_n] = B2[(size_t)(k0 + lb_k + kk) * kD + col0 + lb_n];
        }
        __syncthreads();
        #pragma unroll
        for (int kk = 0; kk < TBK; ++kk) {
            float4 a1 = *(const float4*)&As1[kk][ty * 4];
            float4 a2 = *(const float4*)&As2[kk][ty * 4];
            float4 b1 = *(const float4*)&Bs1[kk][tx * 4];
            float4 b2 = *(const float4*)&Bs2[kk][tx * 4];
            float a1r[4] = {a1.x, a1.y, a1.z, a1.w};
            float a2r[4] = {a2.x, a2.y, a2.z, a2.w};
            float b1r[4] = {b1.x, b1.y, b1.z, b1.w};
            float b2r[4] = {b2.x, b2.y, b2.z, b2.w};
            #pragma unroll
            for (int r = 0; r < 4; ++r)
                #pragma unroll
                for (int c = 0; c < 4; ++c) {
                    acc1[r][c] = fmaf(a1r[r], b1r[c], acc1[r][c]);
                    acc2[r][c] = fmaf(a2r[r], b2r[c], acc2[r][c]);
                }
        }
        __syncthreads();
    }
    #pragma unroll
    for (int r = 0; r < 4; ++r) {
        float4 o;
        o.x = acc1[r][0] * acc2[r][0];
        o.y = acc1[r][1] * acc2[r][1];
        o.z = acc1[r][2] * acc2[r][2];
        o.w = acc1[r][3] * acc2[r][3];
        *(float4*)&C[(size_t)(row0 + ty * 4 + r) * kD + col0 + tx * 4] = o;
    }
}

// ---------------------------------------------------------------------------
// K2: C1 = A@B1, C2 = A@B2 (shared A-operand: ra/rb projections of fused)
// ---------------------------------------------------------------------------
__global__ __launch_bounds__(256)
void k2_dual_proj(const float* __restrict__ A, const float* __restrict__ B1,
                  const float* __restrict__ B2,
                  float* __restrict__ C1, float* __restrict__ C2)
{
    __shared__ float As[TBK][TBM + 4];
    __shared__ float Bs1[TBK][TBN + 4];
    __shared__ float Bs2[TBK][TBN + 4];

    const int tid = threadIdx.x;
    const int tx = tid & 15, ty = tid >> 4;
    const int row0 = blockIdx.y * TBM;
    const int col0 = blockIdx.x * TBN;

    const int la_k = tid & 15, la_m = tid >> 4;
    const int lb_n = tid & 63, lb_k = tid >> 6;

    float acc1[4][4] = {{0.f}}, acc2[4][4] = {{0.f}};

    for (int k0 = 0; k0 < kD; k0 += TBK) {
        #pragma unroll
        for (int mm = 0; mm < TBM; mm += 16)
            As[la_k][la_m + mm] = A[(size_t)(row0 + la_m + mm) * kD + k0 + la_k];
        #pragma unroll
        for (int kk = 0; kk < TBK; kk += 4) {
            Bs1[lb_k + kk][lb_n] = B1[(size_t)(k0 + lb_k + kk) * kD + col0 + lb_n];
            Bs2[lb_k + kk][lb_n] = B2[(size_t)(k0 + lb_k + kk) * kD + col0 + lb_n];
        }
        __syncthreads();
        #pragma unroll
        for (int kk = 0; kk < TBK; ++kk) {
            float4 a = *(const float4*)&As[kk][ty * 4];
            float4 b1 = *(const float4*)&Bs1[kk][tx * 4];
            float4 b2 = *(const float4*)&Bs2[kk][tx * 4];
            float ar[4] = {a.x, a.y, a.z, a.w};
            float b1r[4] = {b1.x, b1.y, b1.z, b1.w};
            float b2r[4] = {b2.x, b2.y, b2.z, b2.w};
            #pragma unroll
            for (int r = 0; r < 4; ++r)
                #pragma unroll
                for (int c = 0; c < 4; ++c) {
                    acc1[r][c] = fmaf(ar[r], b1r[c], acc1[r][c]);
                    acc2[r][c] = fmaf(ar[r], b2r[c], acc2[r][c]);
                }
        }
        __syncthreads();
    }
    #pragma unroll
    for (int r = 0; r < 4; ++r) {
        size_t o = (size_t)(row0 + ty * 4 + r) * kD + col0 + tx * 4;
        float4 o1 = {acc1[r][0], acc1[r][1], acc1[r][2], acc1[r][3]};
        float4 o2 = {acc2[r][0], acc2[r][1], acc2[r][2], acc2[r][3]};
        *(float4*)&C1[o] = o1;
        *(float4*)&C2[o] = o2;
    }
}

// ---------------------------------------------------------------------------
// K3: ba/bb = box @ Wba/Wbb, K=4 -> elementwise
// ---------------------------------------------------------------------------
__global__ __launch_bounds__(256)
void k3_box_proj(const float* __restrict__ box, const float* __restrict__ Wba,
                 const float* __restrict__ Wbb,
                 float* __restrict__ ba, float* __restrict__ bb)
{
    const int r = blockIdx.y;
    const int c = blockIdx.x * 256 + threadIdx.x;
    const float x0 = box[r * 4 + 0], x1 = box[r * 4 + 1];
    const float x2 = box[r * 4 + 2], x3 = box[r * 4 + 3];
    float va = x0 * Wba[c] + x1 * Wba[kD + c] + x2 * Wba[2 * kD + c] + x3 * Wba[3 * kD + c];
    float vb = x0 * Wbb[c] + x1 * Wbb[kD + c] + x2 * Wbb[2 * kD + c] + x3 * Wbb[3 * kD + c];
    ba[(size_t)r * kD + c] = va;
    bb[(size_t)r * kD + c] = vb;
}

// ---------------------------------------------------------------------------
// K4 (MFMA): per block: b, 48-row pair-tile; H = REL[48x2048] @ W0[2048x512]
// via mfma_f32_16x16x32_bf16; REL generated on the fly (never materialized);
// epilogue: score = sum_c W1[c]*tanh(H+b0[c]) reduced in-block, direct store.
// b1 omitted (softmax-invariant). LDS rows padded to 40 bf16 (2-way = free).
// ---------------------------------------------------------------------------
__global__ __launch_bounds__(256)
void k4_scores_mfma(const float* __restrict__ ra, const float* __restrict__ rb,
                    const float* __restrict__ ba, const float* __restrict__ bb,
                    const unsigned short* __restrict__ W0T,
                    const float* __restrict__ b0, const float* __restrict__ W1,
                    float* __restrict__ scores)
{
    __shared__ __align__(16) unsigned short As[48][40];
    __shared__ __align__(16) unsigned short Bs[512][40];
    __shared__ float scoreS[48];

    const int tid  = threadIdx.x;
    const int lane = tid & 63;
    const int w    = tid >> 6;        // wave 0..3, owns cols [w*128, w*128+128)
    const int b    = blockIdx.y;
    const int m0   = blockIdx.x * 48; // pair-row tile within this b (0..1295)

    // --- A-staging slot precompute (48 rows x 8 col-groups = 384 slots) ---
    const int row0 = tid >> 3, cg = tid & 7;           // slot0: rows 0..31
    const bool has1 = (tid < 128);                     // slot1: rows 32..47
    const int row1 = has1 ? row0 + 32 : 0;

    int P0 = m0 + row0; int i0 = P0 / 36, j0 = P0 - i0 * 36;
    int P1 = m0 + row1; int i1 = P1 / 36, j1 = P1 - i1 * 36;
    const float* raP0 = ra + ((size_t)(b * 36 + i0)) * kD;
    const float* rbP0 = rb + ((size_t)(b * 36 + j0)) * kD;
    const float* baP0 = ba + ((size_t)(b * 36 + i0)) * kD;
    const float* bbP0 = bb + ((size_t)(b * 36 + j0)) * kD;
    const float* raP1 = ra + ((size_t)(b * 36 + i1)) * kD;
    const float* rbP1 = rb + ((size_t)(b * 36 + j1)) * kD;
    const float* baP1 = ba + ((size_t)(b * 36 + i1)) * kD;
    const float* bbP1 = bb + ((size_t)(b * 36 + j1)) * kD;

    const int fr = lane & 15;   // fragment row/col within tile
    const int fq = lane >> 4;   // quad

    f32x4 acc[3][8];
    #pragma unroll
    for (int mt = 0; mt < 3; ++mt)
        #pragma unroll
        for (int nt = 0; nt < 8; ++nt)
            acc[mt][nt] = (f32x4)(0.f);

    if (tid < 48) scoreS[tid] = 0.f;

    for (int k0 = 0; k0 < kD; k0 += 32) {
        // stage B: Bs[n][0..32) = W0T[n][k0..k0+32), 2048 x 16B chunks
        #pragma unroll
        for (int c = 0; c < 8; ++c) {
            int chunk = tid + c * 256;
            int n = chunk >> 2, part = chunk & 3;
            *(bf16x8*)&Bs[n][part * 8] =
                *(const bf16x8*)(W0T + (size_t)n * kD + k0 + part * 8);
        }
        // stage A: rel[row][k] = ra_i*rb_j + ba_i*bb_j  -> bf16
        {
            float4 a = *(const float4*)(raP0 + k0 + cg * 4);
            float4 r = *(const float4*)(rbP0 + k0 + cg * 4);
            float4 p = *(const float4*)(baP0 + k0 + cg * 4);
            float4 q = *(const float4*)(bbP0 + k0 + cg * 4);
            ushort4 o;
            o.x = f2bf(a.x * r.x + p.x * q.x);
            o.y = f2bf(a.y * r.y + p.y * q.y);
            o.z = f2bf(a.z * r.z + p.z * q.z);
            o.w = f2bf(a.w * r.w + p.w * q.w);
            *(ushort4*)&As[row0][cg * 4] = o;
        }
        if (has1) {
            float4 a = *(const float4*)(raP1 + k0 + cg * 4);
            float4 r = *(const float4*)(rbP1 + k0 + cg * 4);
            float4 p = *(const float4*)(baP1 + k0 + cg * 4);
            float4 q = *(const float4*)(bbP1 + k0 + cg * 4);
            ushort4 o;
            o.x = f2bf(a.x * r.x + p.x * q.x);
            o.y = f2bf(a.y * r.y + p.y * q.y);
            o.z = f2bf(a.z * r.z + p.z * q.z);
            o.w = f2bf(a.w * r.w + p.w * q.w);
            *(ushort4*)&As[row1][cg * 4] = o;
        }
        __syncthreads();

        bf16x8 a0 = *(bf16x8*)&As[fr     ][fq * 8];
        bf16x8 a1 = *(bf16x8*)&As[16 + fr][fq * 8];
        bf16x8 a2 = *(bf16x8*)&As[32 + fr][fq * 8];
        #pragma unroll
        for (int nt = 0; nt < 8; ++nt) {
            bf16x8 bf = *(bf16x8*)&Bs[w * 128 + nt * 16 + fr][fq * 8];
            acc[0][nt] = __builtin_amdgcn_mfma_f32_16x16x32_bf16(a0, bf, acc[0][nt], 0, 0, 0);
            acc[1][nt] = __builtin_amdgcn_mfma_f32_16x16x32_bf16(a1, bf, acc[1][nt], 0, 0, 0);
            acc[2][nt] = __builtin_amdgcn_mfma_f32_16x16x32_bf16(a2, bf, acc[2][nt], 0, 0, 0);
        }
        __syncthreads();
    }

    // epilogue: score_row = sum_cols W1*tanh(H + b0)
    float b0v[8], w1v[8];
    #pragma unroll
    for (int nt = 0; nt < 8; ++nt) {
        int col = w * 128 + nt * 16 + fr;
        b0v[nt] = b0[col];
        w1v[nt] = W1[col];
    }
    #pragma unroll
    for (int mt = 0; mt < 3; ++mt) {
        #pragma unroll
        for (int reg = 0; reg < 4; ++reg) {
            float p = 0.f;
            #pragma unroll
            for (int nt = 0; nt < 8; ++nt)
                p += w1v[nt] * tanhf(acc[mt][nt][reg] + b0v[nt]);
            p += __shfl_xor(p, 1, 64);
            p += __shfl_xor(p, 2, 64);
            p += __shfl_xor(p, 4, 64);
            p += __shfl_xor(p, 8, 64);
            if (fr == 0)
                atomicAdd(&scoreS[mt * 16 + fq * 4 + reg], p);
        }
    }
    __syncthreads();
    if (tid < 48)
        scores[(size_t)b * 1296 + m0 + tid] = scoreS[tid];
}

// ---------------------------------------------------------------------------
// K5: att[b,i,:] = softmax_j(scores[b,i,:])
// ---------------------------------------------------------------------------
__global__ __launch_bounds__(64)
void k5_softmax(const float* __restrict__ scores, float* __restrict__ att)
{
    const int bi = blockIdx.x;
    const int tid = threadIdx.x;
    float s = (tid < kN) ? scores[(size_t)bi * kN + tid] : -1e30f;
    float m = s;
    #pragma unroll
    for (int off = 32; off >= 1; off >>= 1)
        m = fmaxf(m, __shfl_xor(m, off, 64));
    float e = (tid < kN) ? expf(s - m) : 0.f;
    float sum = e;
    #pragma unroll
    for (int off = 32; off >= 1; off >>= 1)
        sum += __shfl_xor(sum, off, 64);
    if (tid < kN) att[(size_t)bi * kN + tid] = e / sum;
}

// ---------------------------------------------------------------------------
// K6: out[b,i,:] = obj + fused + ra_i.(att_i @ RB_b) + ba_i.(att_i @ BB_b)
// ---------------------------------------------------------------------------
__global__ __launch_bounds__(256)
void k6_output(const float* __restrict__ obj, const float* __restrict__ fused,
               const float* __restrict__ ra, const float* __restrict__ ba,
               const float* __restrict__ rb, const float* __restrict__ bb,
               const float* __restrict__ att, float* __restrict__ out)
{
    __shared__ float attS[kN];
    const int bi = blockIdx.x;
    const int b = bi / kN;
    const int tid = threadIdx.x;
    if (tid < kN) attS[tid] = att[(size_t)bi * kN + tid];
    __syncthreads();
    for (int d = tid; d < kD; d += 256) {
        float s1 = 0.f, s2 = 0.f;
        #pragma unroll 4
        for (int j = 0; j < kN; ++j) {
            float a = attS[j];
            size_t rrow = (size_t)(b * kN + j) * kD + d;
            s1 = fmaf(a, rb[rrow], s1);
            s2 = fmaf(a, bb[rrow], s2);
        }
        size_t o = (size_t)bi * kD + d;
        out[o] = obj[o] + fused[o] + ra[o] * s1 + ba[o] * s2;
    }
}

// ---------------------------------------------------------------------------
extern "C" void kernel_launch(void* const* d_in, const int* in_sizes, int n_in,
                              void* d_out, int out_size, void* d_ws, size_t ws_size,
                              hipStream_t stream)
{
    const float* q   = (const float*)d_in[0];   // [2304, 2048]
    const float* obj = (const float*)d_in[1];   // [64, 36, 2048]
    const float* box = (const float*)d_in[2];   // [64, 36, 4]
    const float* Wq  = (const float*)d_in[3];
    const float* Wo  = (const float*)d_in[4];
    const float* Wfa = (const float*)d_in[5];
    const float* Wfb = (const float*)d_in[6];
    const float* Wba = (const float*)d_in[7];
    const float* Wbb = (const float*)d_in[8];
    const float* W0  = (const float*)d_in[9];
    const float* b0v = (const float*)d_in[10];
    const float* W1  = (const float*)d_in[11];
    // d_in[12] = b1: softmax-invariant, unused. d_in[13..14]: scalars, unused.
    float* out = (float*)d_out;

    // Workspace: 5 x [2304*2048] f32 + scores/att + W0T bf16 (~97 MiB)
    float* ws = (float*)d_ws;
    size_t off = 0;
    float* fused  = ws + off; off += (size_t)kBN * kD;
    float* ra     = ws + off; off += (size_t)kBN * kD;
    float* rb     = ws + off; off += (size_t)kBN * kD;
    float* ba     = ws + off; off += (size_t)kBN * kD;
    float* bb     = ws + off; off += (size_t)kBN * kD;
    float* scores = ws + off; off += (size_t)kBN * kN;
    float* att    = ws + off; off += (size_t)kBN * kN;
    unsigned short* W0T = (unsigned short*)(ws + off);  // [512][2048] bf16

    k0_w0t<<<dim3(kD / 64, kDatt / 64), 256, 0, stream>>>(W0, W0T);

    dim3 gG(kD / TBN, kBN / TBM);  // (32, 36)
    k1_fused_gemm<<<gG, 256, 0, stream>>>(q, Wq, obj, Wo, fused);
    k2_dual_proj <<<gG, 256, 0, stream>>>(fused, Wfa, Wfb, ra, rb);
    k3_box_proj  <<<dim3(kD / 256, kBN), 256, 0, stream>>>(box, Wba, Wbb, ba, bb);
    k4_scores_mfma<<<dim3(27, kB), 256, 0, stream>>>(ra, rb, ba, bb, W0T, b0v, W1, scores);
    k5_softmax   <<<kBN, 64, 0, stream>>>(scores, att);
    k6_output    <<<kBN, 256, 0, stream>>>(obj, fused, ra, ba, rb, bb, att, out);
}

// Round 3
// 1016.974 us; speedup vs baseline: 5.4093x; 1.7535x over previous
//
#include <hip/hip_runtime.h>
#include <hip/hip_bf16.h>
#include <math.h>

constexpr int kB    = 64;
constexpr int kN    = 36;
constexpr int kBN   = kB * kN;   // 2304
constexpr int kD    = 2048;
constexpr int kDatt = 512;

using bf16x8 = __attribute__((ext_vector_type(8))) short;
using f32x4  = __attribute__((ext_vector_type(4))) float;

typedef unsigned int u32;
typedef __attribute__((address_space(3))) u32 lds_u32;
typedef const __attribute__((address_space(1))) u32 glb_u32;

__device__ inline unsigned short f2bf(float f) {
    union { float f; unsigned u; } v; v.f = f;
    unsigned r = v.u + 0x7FFFu + ((v.u >> 16) & 1u);   // RNE
    return (unsigned short)(r >> 16);
}

// ---------------------------------------------------------------------------
// kcvt: f32 -> bf16 elementwise (4 elems/thread)
// ---------------------------------------------------------------------------
__global__ __launch_bounds__(256)
void kcvt(const float* __restrict__ x, unsigned short* __restrict__ y, int n4)
{
    int i = blockIdx.x * 256 + threadIdx.x;
    if (i < n4) {
        float4 v = ((const float4*)x)[i];
        ushort4 o = {f2bf(v.x), f2bf(v.y), f2bf(v.z), f2bf(v.w)};
        ((ushort4*)y)[i] = o;
    }
}

// ---------------------------------------------------------------------------
// ktrp: W[kD][nt] f32 -> WT[nt][kD] bf16 (transpose + convert)
// ---------------------------------------------------------------------------
__global__ __launch_bounds__(256)
void ktrp(const float* __restrict__ W, unsigned short* __restrict__ WT, int nt)
{
    __shared__ float T[64][65];
    const int k0 = blockIdx.x * 64;   // over kD
    const int n0 = blockIdx.y * 64;   // over nt
    const int c = threadIdx.x & 63, r0 = threadIdx.x >> 6;
    #pragma unroll
    for (int rr = 0; rr < 64; rr += 4)
        T[r0 + rr][c] = W[(size_t)(k0 + r0 + rr) * nt + n0 + c];
    __syncthreads();
    #pragma unroll
    for (int rr = 0; rr < 64; rr += 4)
        WT[(size_t)(n0 + r0 + rr) * kD + k0 + c] = f2bf(T[c][r0 + rr]);
}

// ---------------------------------------------------------------------------
// K3: ba/bb = box @ Wba/Wbb, K=4 -> elementwise
// ---------------------------------------------------------------------------
__global__ __launch_bounds__(256)
void k3_box_proj(const float* __restrict__ box, const float* __restrict__ Wba,
                 const float* __restrict__ Wbb,
                 float* __restrict__ ba, float* __restrict__ bb)
{
    const int r = blockIdx.y;
    const int c = blockIdx.x * 256 + threadIdx.x;
    const float x0 = box[r * 4 + 0], x1 = box[r * 4 + 1];
    const float x2 = box[r * 4 + 2], x3 = box[r * 4 + 3];
    float va = x0 * Wba[c] + x1 * Wba[kD + c] + x2 * Wba[2 * kD + c] + x3 * Wba[3 * kD + c];
    float vb = x0 * Wbb[c] + x1 * Wbb[kD + c] + x2 * Wbb[2 * kD + c] + x3 * Wbb[3 * kD + c];
    ba[(size_t)r * kD + c] = va;
    bb[(size_t)r * kD + c] = vb;
}

// ---------------------------------------------------------------------------
// Staging helper: wave `w` stages rows [w*32, w*32+32) of a 128x32 bf16 tile
// via global_load_lds width=16. LDS dest = uniform base + lane*16B.
// ---------------------------------------------------------------------------
__device__ inline void stage128x32(const unsigned short* __restrict__ g,
                                   int grow0, int k0,
                                   unsigned short* lds, int w, int lane)
{
    const int sr = lane >> 2;             // +row within 16-row chunk
    const int sc = (lane & 3) * 8;        // short offset within row
    #pragma unroll
    for (int t = 0; t < 2; ++t) {
        int r = w * 32 + t * 16;
        const unsigned short* gp = g + (size_t)(grow0 + r + sr) * kD + k0 + sc;
        unsigned short* lp = lds + (size_t)r * 32;   // + lane*8 shorts implicit
        __builtin_amdgcn_global_load_lds((glb_u32*)gp, (lds_u32*)lp, 16, 0, 0);
    }
}

// ---------------------------------------------------------------------------
// K1 (MFMA dual): fused = (Qb @ WqT') .* (Ob @ WoT'), writes f32 + bf16
// 128x128 tile, BK=32, mfma_f32_16x16x32_bf16, 4 waves in 2x2
// ---------------------------------------------------------------------------
__global__ __launch_bounds__(256, 1)
void k1_dual_mfma(const unsigned short* __restrict__ Qb,
                  const unsigned short* __restrict__ WqT,
                  const unsigned short* __restrict__ Ob,
                  const unsigned short* __restrict__ WoT,
                  float* __restrict__ fused, unsigned short* __restrict__ fusedb)
{
    __shared__ __align__(16) unsigned short As1[128][32];
    __shared__ __align__(16) unsigned short As2[128][32];
    __shared__ __align__(16) unsigned short Bs1[128][32];
    __shared__ __align__(16) unsigned short Bs2[128][32];

    const int tid = threadIdx.x;
    const int lane = tid & 63;
    const int w = tid >> 6;
    const int wm = w >> 1, wn = w & 1;
    const int row0 = blockIdx.y * 128;
    const int col0 = blockIdx.x * 128;

    f32x4 acc1[4][4], acc2[4][4];
    #pragma unroll
    for (int mt = 0; mt < 4; ++mt)
        #pragma unroll
        for (int nt = 0; nt < 4; ++nt) { acc1[mt][nt] = (f32x4)(0.f); acc2[mt][nt] = (f32x4)(0.f); }

    const int fr = lane & 15, ko = (lane >> 4) * 8;

    for (int k0 = 0; k0 < kD; k0 += 32) {
        stage128x32(Qb,  row0, k0, &As1[0][0], w, lane);
        stage128x32(Ob,  row0, k0, &As2[0][0], w, lane);
        stage128x32(WqT, col0, k0, &Bs1[0][0], w, lane);
        stage128x32(WoT, col0, k0, &Bs2[0][0], w, lane);
        __syncthreads();

        bf16x8 a1[4], a2[4];
        #pragma unroll
        for (int mt = 0; mt < 4; ++mt) {
            a1[mt] = *(bf16x8*)&As1[wm * 64 + mt * 16 + fr][ko];
            a2[mt] = *(bf16x8*)&As2[wm * 64 + mt * 16 + fr][ko];
        }
        #pragma unroll
        for (int nt = 0; nt < 4; ++nt) {
            bf16x8 b1 = *(bf16x8*)&Bs1[wn * 64 + nt * 16 + fr][ko];
            bf16x8 b2 = *(bf16x8*)&Bs2[wn * 64 + nt * 16 + fr][ko];
            #pragma unroll
            for (int mt = 0; mt < 4; ++mt) {
                acc1[mt][nt] = __builtin_amdgcn_mfma_f32_16x16x32_bf16(a1[mt], b1, acc1[mt][nt], 0, 0, 0);
                acc2[mt][nt] = __builtin_amdgcn_mfma_f32_16x16x32_bf16(a2[mt], b2, acc2[mt][nt], 0, 0, 0);
            }
        }
        __syncthreads();
    }

    #pragma unroll
    for (int mt = 0; mt < 4; ++mt)
        #pragma unroll
        for (int nt = 0; nt < 4; ++nt) {
            int row = row0 + wm * 64 + mt * 16 + (lane >> 4) * 4;
            int col = col0 + wn * 64 + nt * 16 + (lane & 15);
            #pragma unroll
            for (int reg = 0; reg < 4; ++reg) {
                float v = acc1[mt][nt][reg] * acc2[mt][nt][reg];
                size_t o = (size_t)(row + reg) * kD + col;
                fused[o] = v;
                fusedb[o] = f2bf(v);
            }
        }
}

// ---------------------------------------------------------------------------
// K2 (MFMA dual-B): ra = Fb @ WfaT', rb = Fb @ WfbT' (shared A staging)
// ---------------------------------------------------------------------------
__global__ __launch_bounds__(256, 1)
void k2_dual_mfma(const unsigned short* __restrict__ Fb,
                  const unsigned short* __restrict__ WfaT,
                  const unsigned short* __restrict__ WfbT,
                  float* __restrict__ ra, float* __restrict__ rb)
{
    __shared__ __align__(16) unsigned short As [128][32];
    __shared__ __align__(16) unsigned short Bs1[128][32];
    __shared__ __align__(16) unsigned short Bs2[128][32];

    const int tid = threadIdx.x;
    const int lane = tid & 63;
    const int w = tid >> 6;
    const int wm = w >> 1, wn = w & 1;
    const int row0 = blockIdx.y * 128;
    const int col0 = blockIdx.x * 128;

    f32x4 acc1[4][4], acc2[4][4];
    #pragma unroll
    for (int mt = 0; mt < 4; ++mt)
        #pragma unroll
        for (int nt = 0; nt < 4; ++nt) { acc1[mt][nt] = (f32x4)(0.f); acc2[mt][nt] = (f32x4)(0.f); }

    const int fr = lane & 15, ko = (lane >> 4) * 8;

    for (int k0 = 0; k0 < kD; k0 += 32) {
        stage128x32(Fb,   row0, k0, &As [0][0], w, lane);
        stage128x32(WfaT, col0, k0, &Bs1[0][0], w, lane);
        stage128x32(WfbT, col0, k0, &Bs2[0][0], w, lane);
        __syncthreads();

        bf16x8 a[4];
        #pragma unroll
        for (int mt = 0; mt < 4; ++mt)
            a[mt] = *(bf16x8*)&As[wm * 64 + mt * 16 + fr][ko];
        #pragma unroll
        for (int nt = 0; nt < 4; ++nt) {
            bf16x8 b1 = *(bf16x8*)&Bs1[wn * 64 + nt * 16 + fr][ko];
            bf16x8 b2 = *(bf16x8*)&Bs2[wn * 64 + nt * 16 + fr][ko];
            #pragma unroll
            for (int mt = 0; mt < 4; ++mt) {
                acc1[mt][nt] = __builtin_amdgcn_mfma_f32_16x16x32_bf16(a[mt], b1, acc1[mt][nt], 0, 0, 0);
                acc2[mt][nt] = __builtin_amdgcn_mfma_f32_16x16x32_bf16(a[mt], b2, acc2[mt][nt], 0, 0, 0);
            }
        }
        __syncthreads();
    }

    #pragma unroll
    for (int mt = 0; mt < 4; ++mt)
        #pragma unroll
        for (int nt = 0; nt < 4; ++nt) {
            int row = row0 + wm * 64 + mt * 16 + (lane >> 4) * 4;
            int col = col0 + wn * 64 + nt * 16 + (lane & 15);
            #pragma unroll
            for (int reg = 0; reg < 4; ++reg) {
                size_t o = (size_t)(row + reg) * kD + col;
                ra[o] = acc1[mt][nt][reg];
                rb[o] = acc2[mt][nt][reg];
            }
        }
}

// ---------------------------------------------------------------------------
// K4 (MFMA): per block: b, 48-row pair-tile; H = REL[48x2048] @ W0[2048x512]
// REL generated on the fly; epilogue: score = sum_c W1[c]*tanh(H+b0[c]).
// ---------------------------------------------------------------------------
__global__ __launch_bounds__(256)
void k4_scores_mfma(const float* __restrict__ ra, const float* __restrict__ rb,
                    const float* __restrict__ ba, const float* __restrict__ bb,
                    const unsigned short* __restrict__ W0T,
                    const float* __restrict__ b0, const float* __restrict__ W1,
                    float* __restrict__ scores)
{
    __shared__ __align__(16) unsigned short As[48][40];
    __shared__ __align__(16) unsigned short Bs[512][40];
    __shared__ float scoreS[48];

    const int tid  = threadIdx.x;
    const int lane = tid & 63;
    const int w    = tid >> 6;
    const int b    = blockIdx.y;
    const int m0   = blockIdx.x * 48;

    const int row0 = tid >> 3, cg = tid & 7;
    const bool has1 = (tid < 128);
    const int row1 = has1 ? row0 + 32 : 0;

    int P0 = m0 + row0; int i0 = P0 / 36, j0 = P0 - i0 * 36;
    int P1 = m0 + row1; int i1 = P1 / 36, j1 = P1 - i1 * 36;
    const float* raP0 = ra + ((size_t)(b * 36 + i0)) * kD;
    const float* rbP0 = rb + ((size_t)(b * 36 + j0)) * kD;
    const float* baP0 = ba + ((size_t)(b * 36 + i0)) * kD;
    const float* bbP0 = bb + ((size_t)(b * 36 + j0)) * kD;
    const float* raP1 = ra + ((size_t)(b * 36 + i1)) * kD;
    const float* rbP1 = rb + ((size_t)(b * 36 + j1)) * kD;
    const float* baP1 = ba + ((size_t)(b * 36 + i1)) * kD;
    const float* bbP1 = bb + ((size_t)(b * 36 + j1)) * kD;

    const int fr = lane & 15;
    const int fq = lane >> 4;

    f32x4 acc[3][8];
    #pragma unroll
    for (int mt = 0; mt < 3; ++mt)
        #pragma unroll
        for (int nt = 0; nt < 8; ++nt)
            acc[mt][nt] = (f32x4)(0.f);

    if (tid < 48) scoreS[tid] = 0.f;

    for (int k0 = 0; k0 < kD; k0 += 32) {
        #pragma unroll
        for (int c = 0; c < 8; ++c) {
            int chunk = tid + c * 256;
            int n = chunk >> 2, part = chunk & 3;
            *(bf16x8*)&Bs[n][part * 8] =
                *(const bf16x8*)(W0T + (size_t)n * kD + k0 + part * 8);
        }
        {
            float4 a = *(const float4*)(raP0 + k0 + cg * 4);
            float4 r = *(const float4*)(rbP0 + k0 + cg * 4);
            float4 p = *(const float4*)(baP0 + k0 + cg * 4);
            float4 q = *(const float4*)(bbP0 + k0 + cg * 4);
            ushort4 o;
            o.x = f2bf(a.x * r.x + p.x * q.x);
            o.y = f2bf(a.y * r.y + p.y * q.y);
            o.z = f2bf(a.z * r.z + p.z * q.z);
            o.w = f2bf(a.w * r.w + p.w * q.w);
            *(ushort4*)&As[row0][cg * 4] = o;
        }
        if (has1) {
            float4 a = *(const float4*)(raP1 + k0 + cg * 4);
            float4 r = *(const float4*)(rbP1 + k0 + cg * 4);
            float4 p = *(const float4*)(baP1 + k0 + cg * 4);
            float4 q = *(const float4*)(bbP1 + k0 + cg * 4);
            ushort4 o;
            o.x = f2bf(a.x * r.x + p.x * q.x);
            o.y = f2bf(a.y * r.y + p.y * q.y);
            o.z = f2bf(a.z * r.z + p.z * q.z);
            o.w = f2bf(a.w * r.w + p.w * q.w);
            *(ushort4*)&As[row1][cg * 4] = o;
        }
        __syncthreads();

        bf16x8 a0 = *(bf16x8*)&As[fr     ][fq * 8];
        bf16x8 a1 = *(bf16x8*)&As[16 + fr][fq * 8];
        bf16x8 a2 = *(bf16x8*)&As[32 + fr][fq * 8];
        #pragma unroll
        for (int nt = 0; nt < 8; ++nt) {
            bf16x8 bf = *(bf16x8*)&Bs[w * 128 + nt * 16 + fr][fq * 8];
            acc[0][nt] = __builtin_amdgcn_mfma_f32_16x16x32_bf16(a0, bf, acc[0][nt], 0, 0, 0);
            acc[1][nt] = __builtin_amdgcn_mfma_f32_16x16x32_bf16(a1, bf, acc[1][nt], 0, 0, 0);
            acc[2][nt] = __builtin_amdgcn_mfma_f32_16x16x32_bf16(a2, bf, acc[2][nt], 0, 0, 0);
        }
        __syncthreads();
    }

    float b0v[8], w1v[8];
    #pragma unroll
    for (int nt = 0; nt < 8; ++nt) {
        int col = w * 128 + nt * 16 + fr;
        b0v[nt] = b0[col];
        w1v[nt] = W1[col];
    }
    #pragma unroll
    for (int mt = 0; mt < 3; ++mt) {
        #pragma unroll
        for (int reg = 0; reg < 4; ++reg) {
            float p = 0.f;
            #pragma unroll
            for (int nt = 0; nt < 8; ++nt)
                p += w1v[nt] * tanhf(acc[mt][nt][reg] + b0v[nt]);
            p += __shfl_xor(p, 1, 64);
            p += __shfl_xor(p, 2, 64);
            p += __shfl_xor(p, 4, 64);
            p += __shfl_xor(p, 8, 64);
            if (fr == 0)
                atomicAdd(&scoreS[mt * 16 + fq * 4 + reg], p);
        }
    }
    __syncthreads();
    if (tid < 48)
        scores[(size_t)b * 1296 + m0 + tid] = scoreS[tid];
}

// ---------------------------------------------------------------------------
// K5: softmax over j
// ---------------------------------------------------------------------------
__global__ __launch_bounds__(64)
void k5_softmax(const float* __restrict__ scores, float* __restrict__ att)
{
    const int bi = blockIdx.x;
    const int tid = threadIdx.x;
    float s = (tid < kN) ? scores[(size_t)bi * kN + tid] : -1e30f;
    float m = s;
    #pragma unroll
    for (int off = 32; off >= 1; off >>= 1)
        m = fmaxf(m, __shfl_xor(m, off, 64));
    float e = (tid < kN) ? expf(s - m) : 0.f;
    float sum = e;
    #pragma unroll
    for (int off = 32; off >= 1; off >>= 1)
        sum += __shfl_xor(sum, off, 64);
    if (tid < kN) att[(size_t)bi * kN + tid] = e / sum;
}

// ---------------------------------------------------------------------------
// K6: out[b,i,:] = obj + fused + ra_i.(att_i @ RB_b) + ba_i.(att_i @ BB_b)
// ---------------------------------------------------------------------------
__global__ __launch_bounds__(256)
void k6_output(const float* __restrict__ obj, const float* __restrict__ fused,
               const float* __restrict__ ra, const float* __restrict__ ba,
               const float* __restrict__ rb, const float* __restrict__ bb,
               const float* __restrict__ att, float* __restrict__ out)
{
    __shared__ float attS[kN];
    const int bi = blockIdx.x;
    const int b = bi / kN;
    const int tid = threadIdx.x;
    if (tid < kN) attS[tid] = att[(size_t)bi * kN + tid];
    __syncthreads();
    for (int d = tid; d < kD; d += 256) {
        float s1 = 0.f, s2 = 0.f;
        #pragma unroll 4
        for (int j = 0; j < kN; ++j) {
            float a = attS[j];
            size_t rrow = (size_t)(b * kN + j) * kD + d;
            s1 = fmaf(a, rb[rrow], s1);
            s2 = fmaf(a, bb[rrow], s2);
        }
        size_t o = (size_t)bi * kD + d;
        out[o] = obj[o] + fused[o] + ra[o] * s1 + ba[o] * s2;
    }
}

// ---------------------------------------------------------------------------
extern "C" void kernel_launch(void* const* d_in, const int* in_sizes, int n_in,
                              void* d_out, int out_size, void* d_ws, size_t ws_size,
                              hipStream_t stream)
{
    const float* q   = (const float*)d_in[0];
    const float* obj = (const float*)d_in[1];
    const float* box = (const float*)d_in[2];
    const float* Wq  = (const float*)d_in[3];
    const float* Wo  = (const float*)d_in[4];
    const float* Wfa = (const float*)d_in[5];
    const float* Wfb = (const float*)d_in[6];
    const float* Wba = (const float*)d_in[7];
    const float* Wbb = (const float*)d_in[8];
    const float* W0  = (const float*)d_in[9];
    const float* b0v = (const float*)d_in[10];
    const float* W1  = (const float*)d_in[11];
    // d_in[12] = b1 (softmax-invariant), d_in[13..14] scalars: unused
    float* out = (float*)d_out;

    const size_t nBD = (size_t)kBN * kD;          // 4718592
    float* ws = (float*)d_ws;
    size_t off = 0;
    float* fused  = ws + off; off += nBD;
    float* ra     = ws + off; off += nBD;
    float* rb     = ws + off; off += nBD;
    float* ba     = ws + off; off += nBD;
    float* bb     = ws + off; off += nBD;
    float* scores = ws + off; off += (size_t)kBN * kN;
    float* att    = ws + off; off += (size_t)kBN * kN;

    unsigned short* us = (unsigned short*)(ws + off);
    size_t uoff = 0;
    unsigned short* W0T     = us + uoff; uoff += (size_t)kDatt * kD;   // 1M
    unsigned short* q_bf    = us + uoff; uoff += nBD;
    unsigned short* obj_bf  = us + uoff; uoff += nBD;
    unsigned short* fusedbf = us + uoff; uoff += nBD;
    unsigned short* WqT     = us + uoff; uoff += (size_t)kD * kD;
    unsigned short* WoT     = us + uoff; uoff += (size_t)kD * kD;
    // WfaT/WfbT alias q_bf/obj_bf (dead after k1; stream order guarantees safety)
    unsigned short* WfaT = q_bf;
    unsigned short* WfbT = obj_bf;

    const int n4 = (int)(nBD / 4);
    kcvt<<<dim3((n4 + 255) / 256), 256, 0, stream>>>(q,   q_bf,   n4);
    kcvt<<<dim3((n4 + 255) / 256), 256, 0, stream>>>(obj, obj_bf, n4);
    ktrp<<<dim3(32, 32), 256, 0, stream>>>(Wq, WqT, kD);
    ktrp<<<dim3(32, 32), 256, 0, stream>>>(Wo, WoT, kD);
    ktrp<<<dim3(32, 8),  256, 0, stream>>>(W0, W0T, kDatt);
    k3_box_proj<<<dim3(kD / 256, kBN), 256, 0, stream>>>(box, Wba, Wbb, ba, bb);

    k1_dual_mfma<<<dim3(kD / 128, kBN / 128), 256, 0, stream>>>(q_bf, WqT, obj_bf, WoT, fused, fusedbf);

    ktrp<<<dim3(32, 32), 256, 0, stream>>>(Wfa, WfaT, kD);
    ktrp<<<dim3(32, 32), 256, 0, stream>>>(Wfb, WfbT, kD);

    k2_dual_mfma<<<dim3(kD / 128, kBN / 128), 256, 0, stream>>>(fusedbf, WfaT, WfbT, ra, rb);

    k4_scores_mfma<<<dim3(27, kB), 256, 0, stream>>>(ra, rb, ba, bb, W0T, b0v, W1, scores);
    k5_softmax<<<kBN, 64, 0, stream>>>(scores, att);
    k6_output<<<kBN, 256, 0, stream>>>(obj, fused, ra, ba, rb, bb, att, out);
}

// Round 4
// 794.594 us; speedup vs baseline: 6.9232x; 1.2799x over previous
//
#include <hip/hip_runtime.h>
#include <hip/hip_bf16.h>
#include <math.h>

constexpr int kB    = 64;
constexpr int kN    = 36;
constexpr int kBN   = kB * kN;   // 2304
constexpr int kD    = 2048;
constexpr int kDatt = 512;
constexpr int kPairs = kN * kN;  // 1296

using bf16x8 = __attribute__((ext_vector_type(8))) short;
using f32x4  = __attribute__((ext_vector_type(4))) float;

typedef unsigned int u32;
typedef __attribute__((address_space(3))) u32 lds_u32;
typedef const __attribute__((address_space(1))) u32 glb_u32;

__device__ inline unsigned short f2bf(float f) {
    union { float f; unsigned u; } v; v.f = f;
    unsigned r = v.u + 0x7FFFu + ((v.u >> 16) & 1u);   // RNE
    return (unsigned short)(r >> 16);
}

// ---------------------------------------------------------------------------
// kcvt: f32 -> bf16 elementwise
// ---------------------------------------------------------------------------
__global__ __launch_bounds__(256)
void kcvt(const float* __restrict__ x, unsigned short* __restrict__ y, int n4)
{
    int i = blockIdx.x * 256 + threadIdx.x;
    if (i < n4) {
        float4 v = ((const float4*)x)[i];
        ushort4 o = {f2bf(v.x), f2bf(v.y), f2bf(v.z), f2bf(v.w)};
        ((ushort4*)y)[i] = o;
    }
}

// ---------------------------------------------------------------------------
// ktrp: W[kD][nt] f32 -> WT[nt][kD] bf16 (transpose + convert)
// ---------------------------------------------------------------------------
__global__ __launch_bounds__(256)
void ktrp(const float* __restrict__ W, unsigned short* __restrict__ WT, int nt)
{
    __shared__ float T[64][65];
    const int k0 = blockIdx.x * 64;
    const int n0 = blockIdx.y * 64;
    const int c = threadIdx.x & 63, r0 = threadIdx.x >> 6;
    #pragma unroll
    for (int rr = 0; rr < 64; rr += 4)
        T[r0 + rr][c] = W[(size_t)(k0 + r0 + rr) * nt + n0 + c];
    __syncthreads();
    #pragma unroll
    for (int rr = 0; rr < 64; rr += 4)
        WT[(size_t)(n0 + r0 + rr) * kD + k0 + c] = f2bf(T[c][r0 + rr]);
}

// ---------------------------------------------------------------------------
// K3: ba/bb = box @ Wba/Wbb, K=4 -> elementwise
// ---------------------------------------------------------------------------
__global__ __launch_bounds__(256)
void k3_box_proj(const float* __restrict__ box, const float* __restrict__ Wba,
                 const float* __restrict__ Wbb,
                 float* __restrict__ ba, float* __restrict__ bb)
{
    const int r = blockIdx.y;
    const int c = blockIdx.x * 256 + threadIdx.x;
    const float x0 = box[r * 4 + 0], x1 = box[r * 4 + 1];
    const float x2 = box[r * 4 + 2], x3 = box[r * 4 + 3];
    float va = x0 * Wba[c] + x1 * Wba[kD + c] + x2 * Wba[2 * kD + c] + x3 * Wba[3 * kD + c];
    float vb = x0 * Wbb[c] + x1 * Wbb[kD + c] + x2 * Wbb[2 * kD + c] + x3 * Wbb[3 * kD + c];
    ba[(size_t)r * kD + c] = va;
    bb[(size_t)r * kD + c] = vb;
}

// ---------------------------------------------------------------------------
// Staging helpers: Rx32 bf16 tiles via global_load_lds width=16 (4 waves).
// LDS layout MUST be unpadded [R][32] (wave-uniform base + lane*16B).
// ---------------------------------------------------------------------------
__device__ inline void stage128(const unsigned short* __restrict__ g,
                                int grow0, int k0,
                                unsigned short* lds, int w, int lane)
{
    const int sr = lane >> 2, sc = (lane & 3) * 8;
    #pragma unroll
    for (int t = 0; t < 2; ++t) {
        int r = w * 32 + t * 16;
        const unsigned short* gp = g + (size_t)(grow0 + r + sr) * kD + k0 + sc;
        __builtin_amdgcn_global_load_lds((glb_u32*)gp, (lds_u32*)(lds + r * 32), 16, 0, 0);
    }
}
__device__ inline void stage64(const unsigned short* __restrict__ g,
                               int grow0, int k0,
                               unsigned short* lds, int w, int lane)
{
    const int sr = lane >> 2, sc = (lane & 3) * 8;
    int r = w * 16;
    const unsigned short* gp = g + (size_t)(grow0 + r + sr) * kD + k0 + sc;
    __builtin_amdgcn_global_load_lds((glb_u32*)gp, (lds_u32*)(lds + r * 32), 16, 0, 0);
}

// ---------------------------------------------------------------------------
// K1 (MFMA dual): fused_bf16 = bf16((Qb @ WqT') .* (Ob @ WoT'))
// 128x64 tile, BK=32, 4 waves 2x2, grid 32x18 = 576 blocks
// ---------------------------------------------------------------------------
__global__ __launch_bounds__(256, 2)
void k1_dual_mfma(const unsigned short* __restrict__ Qb,
                  const unsigned short* __restrict__ WqT,
                  const unsigned short* __restrict__ Ob,
                  const unsigned short* __restrict__ WoT,
                  unsigned short* __restrict__ fusedb)
{
    __shared__ __align__(16) unsigned short As1[128][32];
    __shared__ __align__(16) unsigned short As2[128][32];
    __shared__ __align__(16) unsigned short Bs1[64][32];
    __shared__ __align__(16) unsigned short Bs2[64][32];

    const int tid = threadIdx.x;
    const int lane = tid & 63;
    const int w = tid >> 6;
    const int wm = w >> 1, wn = w & 1;
    const int row0 = blockIdx.y * 128;
    const int col0 = blockIdx.x * 64;

    f32x4 acc1[4][2], acc2[4][2];
    #pragma unroll
    for (int mt = 0; mt < 4; ++mt)
        #pragma unroll
        for (int nt = 0; nt < 2; ++nt) { acc1[mt][nt] = (f32x4)(0.f); acc2[mt][nt] = (f32x4)(0.f); }

    const int fr = lane & 15, ko = (lane >> 4) * 8;

    for (int k0 = 0; k0 < kD; k0 += 32) {
        stage128(Qb,  row0, k0, &As1[0][0], w, lane);
        stage128(Ob,  row0, k0, &As2[0][0], w, lane);
        stage64 (WqT, col0, k0, &Bs1[0][0], w, lane);
        stage64 (WoT, col0, k0, &Bs2[0][0], w, lane);
        __syncthreads();

        bf16x8 a1[4], a2[4];
        #pragma unroll
        for (int mt = 0; mt < 4; ++mt) {
            a1[mt] = *(bf16x8*)&As1[wm * 64 + mt * 16 + fr][ko];
            a2[mt] = *(bf16x8*)&As2[wm * 64 + mt * 16 + fr][ko];
        }
        #pragma unroll
        for (int nt = 0; nt < 2; ++nt) {
            bf16x8 b1 = *(bf16x8*)&Bs1[wn * 32 + nt * 16 + fr][ko];
            bf16x8 b2 = *(bf16x8*)&Bs2[wn * 32 + nt * 16 + fr][ko];
            #pragma unroll
            for (int mt = 0; mt < 4; ++mt) {
                acc1[mt][nt] = __builtin_amdgcn_mfma_f32_16x16x32_bf16(a1[mt], b1, acc1[mt][nt], 0, 0, 0);
                acc2[mt][nt] = __builtin_amdgcn_mfma_f32_16x16x32_bf16(a2[mt], b2, acc2[mt][nt], 0, 0, 0);
            }
        }
        __syncthreads();
    }

    const int fq = lane >> 4;
    #pragma unroll
    for (int mt = 0; mt < 4; ++mt)
        #pragma unroll
        for (int nt = 0; nt < 2; ++nt) {
            int row = row0 + wm * 64 + mt * 16 + fq * 4;
            int col = col0 + wn * 32 + nt * 16 + fr;
            #pragma unroll
            for (int reg = 0; reg < 4; ++reg) {
                float v = acc1[mt][nt][reg] * acc2[mt][nt][reg];
                fusedb[(size_t)(row + reg) * kD + col] = f2bf(v);
            }
        }
}

// ---------------------------------------------------------------------------
// K2 (MFMA dual-B): ra = Fb @ WfaT', rb = Fb @ WfbT', 128x64 tile
// ---------------------------------------------------------------------------
__global__ __launch_bounds__(256, 2)
void k2_dual_mfma(const unsigned short* __restrict__ Fb,
                  const unsigned short* __restrict__ WfaT,
                  const unsigned short* __restrict__ WfbT,
                  float* __restrict__ ra, float* __restrict__ rb)
{
    __shared__ __align__(16) unsigned short As [128][32];
    __shared__ __align__(16) unsigned short Bs1[64][32];
    __shared__ __align__(16) unsigned short Bs2[64][32];

    const int tid = threadIdx.x;
    const int lane = tid & 63;
    const int w = tid >> 6;
    const int wm = w >> 1, wn = w & 1;
    const int row0 = blockIdx.y * 128;
    const int col0 = blockIdx.x * 64;

    f32x4 acc1[4][2], acc2[4][2];
    #pragma unroll
    for (int mt = 0; mt < 4; ++mt)
        #pragma unroll
        for (int nt = 0; nt < 2; ++nt) { acc1[mt][nt] = (f32x4)(0.f); acc2[mt][nt] = (f32x4)(0.f); }

    const int fr = lane & 15, ko = (lane >> 4) * 8;

    for (int k0 = 0; k0 < kD; k0 += 32) {
        stage128(Fb,   row0, k0, &As [0][0], w, lane);
        stage64 (WfaT, col0, k0, &Bs1[0][0], w, lane);
        stage64 (WfbT, col0, k0, &Bs2[0][0], w, lane);
        __syncthreads();

        bf16x8 a[4];
        #pragma unroll
        for (int mt = 0; mt < 4; ++mt)
            a[mt] = *(bf16x8*)&As[wm * 64 + mt * 16 + fr][ko];
        #pragma unroll
        for (int nt = 0; nt < 2; ++nt) {
            bf16x8 b1 = *(bf16x8*)&Bs1[wn * 32 + nt * 16 + fr][ko];
            bf16x8 b2 = *(bf16x8*)&Bs2[wn * 32 + nt * 16 + fr][ko];
            #pragma unroll
            for (int mt = 0; mt < 4; ++mt) {
                acc1[mt][nt] = __builtin_amdgcn_mfma_f32_16x16x32_bf16(a[mt], b1, acc1[mt][nt], 0, 0, 0);
                acc2[mt][nt] = __builtin_amdgcn_mfma_f32_16x16x32_bf16(a[mt], b2, acc2[mt][nt], 0, 0, 0);
            }
        }
        __syncthreads();
    }

    const int fq = lane >> 4;
    #pragma unroll
    for (int mt = 0; mt < 4; ++mt)
        #pragma unroll
        for (int nt = 0; nt < 2; ++nt) {
            int row = row0 + wm * 64 + mt * 16 + fq * 4;
            int col = col0 + wn * 32 + nt * 16 + fr;
            #pragma unroll
            for (int reg = 0; reg < 4; ++reg) {
                size_t o = (size_t)(row + reg) * kD + col;
                ra[o] = acc1[mt][nt][reg];
                rb[o] = acc2[mt][nt][reg];
            }
        }
}

// ---------------------------------------------------------------------------
// K4 v2: per block (b, 128 pair-rows): H = REL[128x2048] @ W0[2048x512]
// 512 thr = 8 waves (2M x 4N); unpadded LDS; global_load_lds B-staging.
// REL generated on the fly from ra/rb/ba/bb; epilogue tanh/W1 reduce.
// ---------------------------------------------------------------------------
__global__ __launch_bounds__(512, 2)
void k4_scores_mfma(const float* __restrict__ ra, const float* __restrict__ rb,
                    const float* __restrict__ ba, const float* __restrict__ bb,
                    const unsigned short* __restrict__ W0T,
                    const float* __restrict__ b0, const float* __restrict__ W1,
                    float* __restrict__ scores)
{
    __shared__ __align__(16) unsigned short Bs[512][32];    // 32 KB
    __shared__ __align__(16) unsigned short RelS[128][32];  // 8 KB
    __shared__ float scoreS[128];

    const int tid  = threadIdx.x;
    const int lane = tid & 63;
    const int w    = tid >> 6;        // 0..7
    const int wm   = w >> 2;          // 0..1 : M-half
    const int wn   = w & 3;           // 0..3 : N-quarter (128 cols)
    const int b    = blockIdx.y;
    const int m0   = blockIdx.x * 128;  // pair-row tile (last block: 16 valid)

    // A-gen slots: 1024 = 128 rows x 8 col-groups; thread does slots tid, tid+512
    int rowA[2], cgA[2];
    const float *raP[2], *rbP[2], *baP[2], *bbP[2];
    #pragma unroll
    for (int t = 0; t < 2; ++t) {
        int s = tid + t * 512;
        rowA[t] = s >> 3; cgA[t] = s & 7;
        int p = m0 + rowA[t]; if (p >= kPairs) p = kPairs - 1;
        int i = p / 36, j = p - i * 36;
        raP[t] = ra + (size_t)(b * 36 + i) * kD;
        baP[t] = ba + (size_t)(b * 36 + i) * kD;
        rbP[t] = rb + (size_t)(b * 36 + j) * kD;
        bbP[t] = bb + (size_t)(b * 36 + j) * kD;
    }

    const int fr = lane & 15, fq = lane >> 4;

    f32x4 acc[4][8];
    #pragma unroll
    for (int mt = 0; mt < 4; ++mt)
        #pragma unroll
        for (int nt = 0; nt < 8; ++nt)
            acc[mt][nt] = (f32x4)(0.f);

    if (tid < 128) scoreS[tid] = 0.f;

    const int sr = lane >> 2, sc = (lane & 3) * 8;

    for (int k0 = 0; k0 < kD; k0 += 32) {
        // B-stage: wave w stages rows [w*64, w*64+64) of W0T k-slice
        #pragma unroll
        for (int t = 0; t < 4; ++t) {
            int r0 = w * 64 + t * 16;
            const unsigned short* gp = W0T + (size_t)(r0 + sr) * kD + k0 + sc;
            __builtin_amdgcn_global_load_lds((glb_u32*)gp, (lds_u32*)&Bs[r0][0], 16, 0, 0);
        }
        // A-gen: REL rows from rank-2 structure
        #pragma unroll
        for (int t = 0; t < 2; ++t) {
            float4 a = *(const float4*)(raP[t] + k0 + cgA[t] * 4);
            float4 r = *(const float4*)(rbP[t] + k0 + cgA[t] * 4);
            float4 p = *(const float4*)(baP[t] + k0 + cgA[t] * 4);
            float4 q = *(const float4*)(bbP[t] + k0 + cgA[t] * 4);
            ushort4 o;
            o.x = f2bf(a.x * r.x + p.x * q.x);
            o.y = f2bf(a.y * r.y + p.y * q.y);
            o.z = f2bf(a.z * r.z + p.z * q.z);
            o.w = f2bf(a.w * r.w + p.w * q.w);
            *(ushort4*)&RelS[rowA[t]][cgA[t] * 4] = o;
        }
        __syncthreads();

        bf16x8 af[4];
        #pragma unroll
        for (int mt = 0; mt < 4; ++mt)
            af[mt] = *(bf16x8*)&RelS[wm * 64 + mt * 16 + fr][fq * 8];
        #pragma unroll
        for (int nt = 0; nt < 8; ++nt) {
            bf16x8 bf = *(bf16x8*)&Bs[wn * 128 + nt * 16 + fr][fq * 8];
            #pragma unroll
            for (int mt = 0; mt < 4; ++mt)
                acc[mt][nt] = __builtin_amdgcn_mfma_f32_16x16x32_bf16(af[mt], bf, acc[mt][nt], 0, 0, 0);
        }
        __syncthreads();
    }

    // epilogue: score_row = sum_cols W1*tanh(H + b0); b1 softmax-invariant
    float b0v[8], w1v[8];
    #pragma unroll
    for (int nt = 0; nt < 8; ++nt) {
        int col = wn * 128 + nt * 16 + fr;
        b0v[nt] = b0[col];
        w1v[nt] = W1[col];
    }
    #pragma unroll
    for (int mt = 0; mt < 4; ++mt) {
        #pragma unroll
        for (int reg = 0; reg < 4; ++reg) {
            float p = 0.f;
            #pragma unroll
            for (int nt = 0; nt < 8; ++nt)
                p += w1v[nt] * tanhf(acc[mt][nt][reg] + b0v[nt]);
            p += __shfl_xor(p, 1, 64);
            p += __shfl_xor(p, 2, 64);
            p += __shfl_xor(p, 4, 64);
            p += __shfl_xor(p, 8, 64);
            if (fr == 0)
                atomicAdd(&scoreS[wm * 64 + mt * 16 + fq * 4 + reg], p);
        }
    }
    __syncthreads();
    if (tid < 128 && m0 + tid < kPairs)
        scores[(size_t)b * kPairs + m0 + tid] = scoreS[tid];
}

// ---------------------------------------------------------------------------
// K5: softmax over j
// ---------------------------------------------------------------------------
__global__ __launch_bounds__(64)
void k5_softmax(const float* __restrict__ scores, float* __restrict__ att)
{
    const int bi = blockIdx.x;
    const int tid = threadIdx.x;
    float s = (tid < kN) ? scores[(size_t)bi * kN + tid] : -1e30f;
    float m = s;
    #pragma unroll
    for (int off = 32; off >= 1; off >>= 1)
        m = fmaxf(m, __shfl_xor(m, off, 64));
    float e = (tid < kN) ? expf(s - m) : 0.f;
    float sum = e;
    #pragma unroll
    for (int off = 32; off >= 1; off >>= 1)
        sum += __shfl_xor(sum, off, 64);
    if (tid < kN) att[(size_t)bi * kN + tid] = e / sum;
}

// ---------------------------------------------------------------------------
// K6: out[b,i,:] = obj + fused + ra_i.(att_i @ RB_b) + ba_i.(att_i @ BB_b)
// ---------------------------------------------------------------------------
__global__ __launch_bounds__(256)
void k6_output(const float* __restrict__ obj, const unsigned short* __restrict__ fusedb,
               const float* __restrict__ ra, const float* __restrict__ ba,
               const float* __restrict__ rb, const float* __restrict__ bb,
               const float* __restrict__ att, float* __restrict__ out)
{
    __shared__ float attS[kN];
    const int bi = blockIdx.x;
    const int b = bi / kN;
    const int tid = threadIdx.x;
    if (tid < kN) attS[tid] = att[(size_t)bi * kN + tid];
    __syncthreads();
    for (int d = tid; d < kD; d += 256) {
        float s1 = 0.f, s2 = 0.f;
        #pragma unroll 4
        for (int j = 0; j < kN; ++j) {
            float a = attS[j];
            size_t rrow = (size_t)(b * kN + j) * kD + d;
            s1 = fmaf(a, rb[rrow], s1);
            s2 = fmaf(a, bb[rrow], s2);
        }
        size_t o = (size_t)bi * kD + d;
        float fv = __uint_as_float((u32)fusedb[o] << 16);
        out[o] = obj[o] + fv + ra[o] * s1 + ba[o] * s2;
    }
}

// ---------------------------------------------------------------------------
extern "C" void kernel_launch(void* const* d_in, const int* in_sizes, int n_in,
                              void* d_out, int out_size, void* d_ws, size_t ws_size,
                              hipStream_t stream)
{
    const float* q   = (const float*)d_in[0];
    const float* obj = (const float*)d_in[1];
    const float* box = (const float*)d_in[2];
    const float* Wq  = (const float*)d_in[3];
    const float* Wo  = (const float*)d_in[4];
    const float* Wfa = (const float*)d_in[5];
    const float* Wfb = (const float*)d_in[6];
    const float* Wba = (const float*)d_in[7];
    const float* Wbb = (const float*)d_in[8];
    const float* W0  = (const float*)d_in[9];
    const float* b0v = (const float*)d_in[10];
    const float* W1  = (const float*)d_in[11];
    // d_in[12] = b1 (softmax-invariant), d_in[13..14] scalars: unused
    float* out = (float*)d_out;

    const size_t nBD = (size_t)kBN * kD;
    float* ws = (float*)d_ws;
    size_t off = 0;
    float* ra     = ws + off; off += nBD;
    float* rb     = ws + off; off += nBD;
    float* ba     = ws + off; off += nBD;
    float* bb     = ws + off; off += nBD;
    float* scores = ws + off; off += (size_t)kBN * kN;
    float* att    = ws + off; off += (size_t)kBN * kN;

    unsigned short* us = (unsigned short*)(ws + off);
    size_t uoff = 0;
    unsigned short* W0T     = us + uoff; uoff += (size_t)kDatt * kD;
    unsigned short* q_bf    = us + uoff; uoff += nBD;
    unsigned short* obj_bf  = us + uoff; uoff += nBD;
    unsigned short* fusedbf = us + uoff; uoff += nBD;
    unsigned short* WqT     = us + uoff; uoff += (size_t)kD * kD;
    unsigned short* WoT     = us + uoff; uoff += (size_t)kD * kD;
    // WfaT/WfbT alias q_bf/obj_bf (dead after k1; stream order guarantees safety)
    unsigned short* WfaT = q_bf;
    unsigned short* WfbT = obj_bf;

    const int n4 = (int)(nBD / 4);
    kcvt<<<dim3((n4 + 255) / 256), 256, 0, stream>>>(q,   q_bf,   n4);
    kcvt<<<dim3((n4 + 255) / 256), 256, 0, stream>>>(obj, obj_bf, n4);
    ktrp<<<dim3(32, 32), 256, 0, stream>>>(Wq, WqT, kD);
    ktrp<<<dim3(32, 32), 256, 0, stream>>>(Wo, WoT, kD);
    ktrp<<<dim3(32, 8),  256, 0, stream>>>(W0, W0T, kDatt);
    k3_box_proj<<<dim3(kD / 256, kBN), 256, 0, stream>>>(box, Wba, Wbb, ba, bb);

    k1_dual_mfma<<<dim3(kD / 64, kBN / 128), 256, 0, stream>>>(q_bf, WqT, obj_bf, WoT, fusedbf);

    ktrp<<<dim3(32, 32), 256, 0, stream>>>(Wfa, WfaT, kD);
    ktrp<<<dim3(32, 32), 256, 0, stream>>>(Wfb, WfbT, kD);

    k2_dual_mfma<<<dim3(kD / 64, kBN / 128), 256, 0, stream>>>(fusedbf, WfaT, WfbT, ra, rb);

    k4_scores_mfma<<<dim3(11, kB), 512, 0, stream>>>(ra, rb, ba, bb, W0T, b0v, W1, scores);
    k5_softmax<<<kBN, 64, 0, stream>>>(scores, att);
    k6_output<<<kBN, 256, 0, stream>>>(obj, fusedbf, ra, ba, rb, bb, att, out);
}

// Round 5
// 765.737 us; speedup vs baseline: 7.1841x; 1.0377x over previous
//
#include <hip/hip_runtime.h>
#include <hip/hip_bf16.h>
#include <math.h>

constexpr int kB    = 64;
constexpr int kN    = 36;
constexpr int kBN   = kB * kN;   // 2304
constexpr int kD    = 2048;
constexpr int kDatt = 512;
constexpr int kPairs = kN * kN;  // 1296

using bf16x8 = __attribute__((ext_vector_type(8))) short;
using f32x4  = __attribute__((ext_vector_type(4))) float;

typedef unsigned int u32;
typedef __attribute__((address_space(3))) u32 lds_u32;
typedef const __attribute__((address_space(1))) u32 glb_u32;

__device__ inline unsigned short f2bf(float f) {
    union { float f; unsigned u; } v; v.f = f;
    unsigned r = v.u + 0x7FFFu + ((v.u >> 16) & 1u);   // RNE
    return (unsigned short)(r >> 16);
}

// ---------------------------------------------------------------------------
// kcvt: f32 -> bf16 elementwise
// ---------------------------------------------------------------------------
__global__ __launch_bounds__(256)
void kcvt(const float* __restrict__ x, unsigned short* __restrict__ y, int n4)
{
    int i = blockIdx.x * 256 + threadIdx.x;
    if (i < n4) {
        float4 v = ((const float4*)x)[i];
        ushort4 o = {f2bf(v.x), f2bf(v.y), f2bf(v.z), f2bf(v.w)};
        ((ushort4*)y)[i] = o;
    }
}

// ---------------------------------------------------------------------------
// ktrp: W[kD][nt] f32 -> WT[nt][kD] bf16 (transpose + convert)
// ---------------------------------------------------------------------------
__global__ __launch_bounds__(256)
void ktrp(const float* __restrict__ W, unsigned short* __restrict__ WT, int nt)
{
    __shared__ float T[64][65];
    const int k0 = blockIdx.x * 64;
    const int n0 = blockIdx.y * 64;
    const int c = threadIdx.x & 63, r0 = threadIdx.x >> 6;
    #pragma unroll
    for (int rr = 0; rr < 64; rr += 4)
        T[r0 + rr][c] = W[(size_t)(k0 + r0 + rr) * nt + n0 + c];
    __syncthreads();
    #pragma unroll
    for (int rr = 0; rr < 64; rr += 4)
        WT[(size_t)(n0 + r0 + rr) * kD + k0 + c] = f2bf(T[c][r0 + rr]);
}

// ---------------------------------------------------------------------------
// K3: ba/bb = box @ Wba/Wbb, K=4 -> elementwise
// ---------------------------------------------------------------------------
__global__ __launch_bounds__(256)
void k3_box_proj(const float* __restrict__ box, const float* __restrict__ Wba,
                 const float* __restrict__ Wbb,
                 float* __restrict__ ba, float* __restrict__ bb)
{
    const int r = blockIdx.y;
    const int c = blockIdx.x * 256 + threadIdx.x;
    const float x0 = box[r * 4 + 0], x1 = box[r * 4 + 1];
    const float x2 = box[r * 4 + 2], x3 = box[r * 4 + 3];
    float va = x0 * Wba[c] + x1 * Wba[kD + c] + x2 * Wba[2 * kD + c] + x3 * Wba[3 * kD + c];
    float vb = x0 * Wbb[c] + x1 * Wbb[kD + c] + x2 * Wbb[2 * kD + c] + x3 * Wbb[3 * kD + c];
    ba[(size_t)r * kD + c] = va;
    bb[(size_t)r * kD + c] = vb;
}

// ---------------------------------------------------------------------------
// Staging helpers for k1/k2: Rx32 bf16 tiles via global_load_lds width=16.
// ---------------------------------------------------------------------------
__device__ inline void stage128(const unsigned short* __restrict__ g,
                                int grow0, int k0,
                                unsigned short* lds, int w, int lane)
{
    const int sr = lane >> 2, sc = (lane & 3) * 8;
    #pragma unroll
    for (int t = 0; t < 2; ++t) {
        int r = w * 32 + t * 16;
        const unsigned short* gp = g + (size_t)(grow0 + r + sr) * kD + k0 + sc;
        __builtin_amdgcn_global_load_lds((glb_u32*)gp, (lds_u32*)(lds + r * 32), 16, 0, 0);
    }
}
__device__ inline void stage64(const unsigned short* __restrict__ g,
                               int grow0, int k0,
                               unsigned short* lds, int w, int lane)
{
    const int sr = lane >> 2, sc = (lane & 3) * 8;
    int r = w * 16;
    const unsigned short* gp = g + (size_t)(grow0 + r + sr) * kD + k0 + sc;
    __builtin_amdgcn_global_load_lds((glb_u32*)gp, (lds_u32*)(lds + r * 32), 16, 0, 0);
}

// ---------------------------------------------------------------------------
// K1 (MFMA dual): fused_bf16 = bf16((Qb @ WqT') .* (Ob @ WoT')), 128x64 tile
// ---------------------------------------------------------------------------
__global__ __launch_bounds__(256, 2)
void k1_dual_mfma(const unsigned short* __restrict__ Qb,
                  const unsigned short* __restrict__ WqT,
                  const unsigned short* __restrict__ Ob,
                  const unsigned short* __restrict__ WoT,
                  unsigned short* __restrict__ fusedb)
{
    __shared__ __align__(16) unsigned short As1[128][32];
    __shared__ __align__(16) unsigned short As2[128][32];
    __shared__ __align__(16) unsigned short Bs1[64][32];
    __shared__ __align__(16) unsigned short Bs2[64][32];

    const int tid = threadIdx.x;
    const int lane = tid & 63;
    const int w = tid >> 6;
    const int wm = w >> 1, wn = w & 1;
    const int row0 = blockIdx.y * 128;
    const int col0 = blockIdx.x * 64;

    f32x4 acc1[4][2], acc2[4][2];
    #pragma unroll
    for (int mt = 0; mt < 4; ++mt)
        #pragma unroll
        for (int nt = 0; nt < 2; ++nt) { acc1[mt][nt] = (f32x4)(0.f); acc2[mt][nt] = (f32x4)(0.f); }

    const int fr = lane & 15, ko = (lane >> 4) * 8;

    for (int k0 = 0; k0 < kD; k0 += 32) {
        stage128(Qb,  row0, k0, &As1[0][0], w, lane);
        stage128(Ob,  row0, k0, &As2[0][0], w, lane);
        stage64 (WqT, col0, k0, &Bs1[0][0], w, lane);
        stage64 (WoT, col0, k0, &Bs2[0][0], w, lane);
        __syncthreads();

        bf16x8 a1[4], a2[4];
        #pragma unroll
        for (int mt = 0; mt < 4; ++mt) {
            a1[mt] = *(bf16x8*)&As1[wm * 64 + mt * 16 + fr][ko];
            a2[mt] = *(bf16x8*)&As2[wm * 64 + mt * 16 + fr][ko];
        }
        #pragma unroll
        for (int nt = 0; nt < 2; ++nt) {
            bf16x8 b1 = *(bf16x8*)&Bs1[wn * 32 + nt * 16 + fr][ko];
            bf16x8 b2 = *(bf16x8*)&Bs2[wn * 32 + nt * 16 + fr][ko];
            #pragma unroll
            for (int mt = 0; mt < 4; ++mt) {
                acc1[mt][nt] = __builtin_amdgcn_mfma_f32_16x16x32_bf16(a1[mt], b1, acc1[mt][nt], 0, 0, 0);
                acc2[mt][nt] = __builtin_amdgcn_mfma_f32_16x16x32_bf16(a2[mt], b2, acc2[mt][nt], 0, 0, 0);
            }
        }
        __syncthreads();
    }

    const int fq = lane >> 4;
    #pragma unroll
    for (int mt = 0; mt < 4; ++mt)
        #pragma unroll
        for (int nt = 0; nt < 2; ++nt) {
            int row = row0 + wm * 64 + mt * 16 + fq * 4;
            int col = col0 + wn * 32 + nt * 16 + fr;
            #pragma unroll
            for (int reg = 0; reg < 4; ++reg) {
                float v = acc1[mt][nt][reg] * acc2[mt][nt][reg];
                fusedb[(size_t)(row + reg) * kD + col] = f2bf(v);
            }
        }
}

// ---------------------------------------------------------------------------
// K2 (MFMA dual-B): ra = Fb @ WfaT', rb = Fb @ WfbT', 128x64 tile
// ---------------------------------------------------------------------------
__global__ __launch_bounds__(256, 2)
void k2_dual_mfma(const unsigned short* __restrict__ Fb,
                  const unsigned short* __restrict__ WfaT,
                  const unsigned short* __restrict__ WfbT,
                  float* __restrict__ ra, float* __restrict__ rb)
{
    __shared__ __align__(16) unsigned short As [128][32];
    __shared__ __align__(16) unsigned short Bs1[64][32];
    __shared__ __align__(16) unsigned short Bs2[64][32];

    const int tid = threadIdx.x;
    const int lane = tid & 63;
    const int w = tid >> 6;
    const int wm = w >> 1, wn = w & 1;
    const int row0 = blockIdx.y * 128;
    const int col0 = blockIdx.x * 64;

    f32x4 acc1[4][2], acc2[4][2];
    #pragma unroll
    for (int mt = 0; mt < 4; ++mt)
        #pragma unroll
        for (int nt = 0; nt < 2; ++nt) { acc1[mt][nt] = (f32x4)(0.f); acc2[mt][nt] = (f32x4)(0.f); }

    const int fr = lane & 15, ko = (lane >> 4) * 8;

    for (int k0 = 0; k0 < kD; k0 += 32) {
        stage128(Fb,   row0, k0, &As [0][0], w, lane);
        stage64 (WfaT, col0, k0, &Bs1[0][0], w, lane);
        stage64 (WfbT, col0, k0, &Bs2[0][0], w, lane);
        __syncthreads();

        bf16x8 a[4];
        #pragma unroll
        for (int mt = 0; mt < 4; ++mt)
            a[mt] = *(bf16x8*)&As[wm * 64 + mt * 16 + fr][ko];
        #pragma unroll
        for (int nt = 0; nt < 2; ++nt) {
            bf16x8 b1 = *(bf16x8*)&Bs1[wn * 32 + nt * 16 + fr][ko];
            bf16x8 b2 = *(bf16x8*)&Bs2[wn * 32 + nt * 16 + fr][ko];
            #pragma unroll
            for (int mt = 0; mt < 4; ++mt) {
                acc1[mt][nt] = __builtin_amdgcn_mfma_f32_16x16x32_bf16(a[mt], b1, acc1[mt][nt], 0, 0, 0);
                acc2[mt][nt] = __builtin_amdgcn_mfma_f32_16x16x32_bf16(a[mt], b2, acc2[mt][nt], 0, 0, 0);
            }
        }
        __syncthreads();
    }

    const int fq = lane >> 4;
    #pragma unroll
    for (int mt = 0; mt < 4; ++mt)
        #pragma unroll
        for (int nt = 0; nt < 2; ++nt) {
            int row = row0 + wm * 64 + mt * 16 + fq * 4;
            int col = col0 + wn * 32 + nt * 16 + fr;
            #pragma unroll
            for (int reg = 0; reg < 4; ++reg) {
                size_t o = (size_t)(row + reg) * kD + col;
                ra[o] = acc1[mt][nt][reg];
                rb[o] = acc2[mt][nt][reg];
            }
        }
}

// ---------------------------------------------------------------------------
// K4 v3: single-barrier software pipeline.
// Per block (b, 128 pair-rows): H = REL[128x2048] @ W0[2048x512].
// Bs double-buffered (glds DMA issued one phase ahead); REL A-operands
// prefetched to VGPRs during MFMA, converted+written to RelS[nxt] after.
// RelS padded to 40 shorts/row to spread write banks. One barrier per K-step.
// ---------------------------------------------------------------------------
__global__ __launch_bounds__(512, 2)
void k4_scores_mfma(const float* __restrict__ ra, const float* __restrict__ rb,
                    const float* __restrict__ ba, const float* __restrict__ bb,
                    const unsigned short* __restrict__ W0T,
                    const float* __restrict__ b0, const float* __restrict__ W1,
                    float* __restrict__ scores)
{
    __shared__ __align__(16) unsigned short Bs[2][512][32];   // 64 KB
    __shared__ __align__(16) unsigned short RelS[2][128][40]; // 20 KB
    __shared__ float scoreS[128];

    const int tid  = threadIdx.x;
    const int lane = tid & 63;
    const int w    = tid >> 6;        // 0..7
    const int wm   = w >> 2;          // 0..1 : M-half
    const int wn   = w & 3;           // 0..3 : N-quarter (128 cols)
    const int b    = blockIdx.y;
    const int m0   = blockIdx.x * 128;  // pair-row tile (last block: 16 valid)

    // A-gen slots: 1024 = 128 rows x 8 col-groups; thread does slots tid, tid+512
    int rowA[2], cgA[2];
    const float *raP[2], *rbP[2], *baP[2], *bbP[2];
    #pragma unroll
    for (int t = 0; t < 2; ++t) {
        int s = tid + t * 512;
        rowA[t] = s >> 3; cgA[t] = s & 7;
        int p = m0 + rowA[t]; if (p >= kPairs) p = kPairs - 1;
        int i = p / 36, j = p - i * 36;
        raP[t] = ra + (size_t)(b * 36 + i) * kD;
        baP[t] = ba + (size_t)(b * 36 + i) * kD;
        rbP[t] = rb + (size_t)(b * 36 + j) * kD;
        bbP[t] = bb + (size_t)(b * 36 + j) * kD;
    }

    const int fr = lane & 15, fq = lane >> 4;
    const int sr = lane >> 2, sc = (lane & 3) * 8;

    f32x4 acc[4][8];
    #pragma unroll
    for (int mt = 0; mt < 4; ++mt)
        #pragma unroll
        for (int nt = 0; nt < 8; ++nt)
            acc[mt][nt] = (f32x4)(0.f);

    if (tid < 128) scoreS[tid] = 0.f;

    float4 pa[2], pr[2], pp[2], pq[2];   // prefetched A-gen operands

    #define ISSUE_B(k0_, buf_)                                                   \
        _Pragma("unroll")                                                        \
        for (int t = 0; t < 4; ++t) {                                            \
            int r0 = w * 64 + t * 16;                                            \
            const unsigned short* gp = W0T + (size_t)(r0 + sr) * kD + (k0_) + sc;\
            __builtin_amdgcn_global_load_lds((glb_u32*)gp,                       \
                (lds_u32*)&Bs[buf_][r0][0], 16, 0, 0);                           \
        }

    #define LOAD_A(k0_)                                                          \
        _Pragma("unroll")                                                        \
        for (int t = 0; t < 2; ++t) {                                            \
            pa[t] = *(const float4*)(raP[t] + (k0_) + cgA[t] * 4);               \
            pr[t] = *(const float4*)(rbP[t] + (k0_) + cgA[t] * 4);               \
            pp[t] = *(const float4*)(baP[t] + (k0_) + cgA[t] * 4);               \
            pq[t] = *(const float4*)(bbP[t] + (k0_) + cgA[t] * 4);               \
        }

    #define WRITE_REL(buf_)                                                      \
        _Pragma("unroll")                                                        \
        for (int t = 0; t < 2; ++t) {                                            \
            ushort4 o;                                                           \
            o.x = f2bf(pa[t].x * pr[t].x + pp[t].x * pq[t].x);                   \
            o.y = f2bf(pa[t].y * pr[t].y + pp[t].y * pq[t].y);                   \
            o.z = f2bf(pa[t].z * pr[t].z + pp[t].z * pq[t].z);                   \
            o.w = f2bf(pa[t].w * pr[t].w + pp[t].w * pq[t].w);                   \
            *(ushort4*)&RelS[buf_][rowA[t]][cgA[t] * 4] = o;                     \
        }

    // prologue: fill buffer 0
    ISSUE_B(0, 0)
    LOAD_A(0)
    WRITE_REL(0)

    for (int k0 = 0; k0 < kD; k0 += 32) {
        const int cur = (k0 >> 5) & 1, nxt = cur ^ 1;
        const bool more = (k0 + 32 < kD);
        __syncthreads();   // Bs[cur] DMA drained; RelS[cur] visible
        if (more) {
            ISSUE_B(k0 + 32, nxt)   // DMA runs during this step's MFMA
            LOAD_A(k0 + 32)         // A-regs in flight during MFMA
        }
        bf16x8 af[4];
        #pragma unroll
        for (int mt = 0; mt < 4; ++mt)
            af[mt] = *(bf16x8*)&RelS[cur][wm * 64 + mt * 16 + fr][fq * 8];
        #pragma unroll
        for (int nt = 0; nt < 8; ++nt) {
            bf16x8 bf = *(bf16x8*)&Bs[cur][wn * 128 + nt * 16 + fr][fq * 8];
            #pragma unroll
            for (int mt = 0; mt < 4; ++mt)
                acc[mt][nt] = __builtin_amdgcn_mfma_f32_16x16x32_bf16(af[mt], bf, acc[mt][nt], 0, 0, 0);
        }
        if (more) { WRITE_REL(nxt) }
    }

    // epilogue: score_row = sum_cols W1*tanh(H + b0); b1 softmax-invariant
    float b0v[8], w1v[8];
    #pragma unroll
    for (int nt = 0; nt < 8; ++nt) {
        int col = wn * 128 + nt * 16 + fr;
        b0v[nt] = b0[col];
        w1v[nt] = W1[col];
    }
    #pragma unroll
    for (int mt = 0; mt < 4; ++mt) {
        #pragma unroll
        for (int reg = 0; reg < 4; ++reg) {
            float p = 0.f;
            #pragma unroll
            for (int nt = 0; nt < 8; ++nt)
                p += w1v[nt] * tanhf(acc[mt][nt][reg] + b0v[nt]);
            p += __shfl_xor(p, 1, 64);
            p += __shfl_xor(p, 2, 64);
            p += __shfl_xor(p, 4, 64);
            p += __shfl_xor(p, 8, 64);
            if (fr == 0)
                atomicAdd(&scoreS[wm * 64 + mt * 16 + fq * 4 + reg], p);
        }
    }
    __syncthreads();
    if (tid < 128 && m0 + tid < kPairs)
        scores[(size_t)b * kPairs + m0 + tid] = scoreS[tid];
}

// ---------------------------------------------------------------------------
// K5: softmax over j
// ---------------------------------------------------------------------------
__global__ __launch_bounds__(64)
void k5_softmax(const float* __restrict__ scores, float* __restrict__ att)
{
    const int bi = blockIdx.x;
    const int tid = threadIdx.x;
    float s = (tid < kN) ? scores[(size_t)bi * kN + tid] : -1e30f;
    float m = s;
    #pragma unroll
    for (int off = 32; off >= 1; off >>= 1)
        m = fmaxf(m, __shfl_xor(m, off, 64));
    float e = (tid < kN) ? expf(s - m) : 0.f;
    float sum = e;
    #pragma unroll
    for (int off = 32; off >= 1; off >>= 1)
        sum += __shfl_xor(sum, off, 64);
    if (tid < kN) att[(size_t)bi * kN + tid] = e / sum;
}

// ---------------------------------------------------------------------------
// K6: out[b,i,:] = obj + fused + ra_i.(att_i @ RB_b) + ba_i.(att_i @ BB_b)
// ---------------------------------------------------------------------------
__global__ __launch_bounds__(256)
void k6_output(const float* __restrict__ obj, const unsigned short* __restrict__ fusedb,
               const float* __restrict__ ra, const float* __restrict__ ba,
               const float* __restrict__ rb, const float* __restrict__ bb,
               const float* __restrict__ att, float* __restrict__ out)
{
    __shared__ float attS[kN];
    const int bi = blockIdx.x;
    const int b = bi / kN;
    const int tid = threadIdx.x;
    if (tid < kN) attS[tid] = att[(size_t)bi * kN + tid];
    __syncthreads();
    for (int d = tid; d < kD; d += 256) {
        float s1 = 0.f, s2 = 0.f;
        #pragma unroll 4
        for (int j = 0; j < kN; ++j) {
            float a = attS[j];
            size_t rrow = (size_t)(b * kN + j) * kD + d;
            s1 = fmaf(a, rb[rrow], s1);
            s2 = fmaf(a, bb[rrow], s2);
        }
        size_t o = (size_t)bi * kD + d;
        float fv = __uint_as_float((u32)fusedb[o] << 16);
        out[o] = obj[o] + fv + ra[o] * s1 + ba[o] * s2;
    }
}

// ---------------------------------------------------------------------------
extern "C" void kernel_launch(void* const* d_in, const int* in_sizes, int n_in,
                              void* d_out, int out_size, void* d_ws, size_t ws_size,
                              hipStream_t stream)
{
    const float* q   = (const float*)d_in[0];
    const float* obj = (const float*)d_in[1];
    const float* box = (const float*)d_in[2];
    const float* Wq  = (const float*)d_in[3];
    const float* Wo  = (const float*)d_in[4];
    const float* Wfa = (const float*)d_in[5];
    const float* Wfb = (const float*)d_in[6];
    const float* Wba = (const float*)d_in[7];
    const float* Wbb = (const float*)d_in[8];
    const float* W0  = (const float*)d_in[9];
    const float* b0v = (const float*)d_in[10];
    const float* W1  = (const float*)d_in[11];
    // d_in[12] = b1 (softmax-invariant), d_in[13..14] scalars: unused
    float* out = (float*)d_out;

    const size_t nBD = (size_t)kBN * kD;
    float* ws = (float*)d_ws;
    size_t off = 0;
    float* ra     = ws + off; off += nBD;
    float* rb     = ws + off; off += nBD;
    float* ba     = ws + off; off += nBD;
    float* bb     = ws + off; off += nBD;
    float* scores = ws + off; off += (size_t)kBN * kN;
    float* att    = ws + off; off += (size_t)kBN * kN;

    unsigned short* us = (unsigned short*)(ws + off);
    size_t uoff = 0;
    unsigned short* W0T     = us + uoff; uoff += (size_t)kDatt * kD;
    unsigned short* q_bf    = us + uoff; uoff += nBD;
    unsigned short* obj_bf  = us + uoff; uoff += nBD;
    unsigned short* fusedbf = us + uoff; uoff += nBD;
    unsigned short* WqT     = us + uoff; uoff += (size_t)kD * kD;
    unsigned short* WoT     = us + uoff; uoff += (size_t)kD * kD;
    // WfaT/WfbT alias q_bf/obj_bf (dead after k1; stream order guarantees safety)
    unsigned short* WfaT = q_bf;
    unsigned short* WfbT = obj_bf;

    const int n4 = (int)(nBD / 4);
    kcvt<<<dim3((n4 + 255) / 256), 256, 0, stream>>>(q,   q_bf,   n4);
    kcvt<<<dim3((n4 + 255) / 256), 256, 0, stream>>>(obj, obj_bf, n4);
    ktrp<<<dim3(32, 32), 256, 0, stream>>>(Wq, WqT, kD);
    ktrp<<<dim3(32, 32), 256, 0, stream>>>(Wo, WoT, kD);
    ktrp<<<dim3(32, 8),  256, 0, stream>>>(W0, W0T, kDatt);
    k3_box_proj<<<dim3(kD / 256, kBN), 256, 0, stream>>>(box, Wba, Wbb, ba, bb);

    k1_dual_mfma<<<dim3(kD / 64, kBN / 128), 256, 0, stream>>>(q_bf, WqT, obj_bf, WoT, fusedbf);

    ktrp<<<dim3(32, 32), 256, 0, stream>>>(Wfa, WfaT, kD);
    ktrp<<<dim3(32, 32), 256, 0, stream>>>(Wfb, WfbT, kD);

    k2_dual_mfma<<<dim3(kD / 64, kBN / 128), 256, 0, stream>>>(fusedbf, WfaT, WfbT, ra, rb);

    k4_scores_mfma<<<dim3(11, kB), 512, 0, stream>>>(ra, rb, ba, bb, W0T, b0v, W1, scores);
    k5_softmax<<<kBN, 64, 0, stream>>>(scores, att);
    k6_output<<<kBN, 256, 0, stream>>>(obj, fusedbf, ra, ba, rb, bb, att, out);
}